// Round 3
// baseline (997.667 us; speedup 1.0000x reference)
//
#include <hip/hip_runtime.h>

#define U16 unsigned short

typedef short bf16x8 __attribute__((ext_vector_type(8)));
typedef float f32x4 __attribute__((ext_vector_type(4)));

// ---------- bf16 helpers ----------
__device__ __forceinline__ float bfp(const U16* p) { return __uint_as_float(((unsigned)(*p)) << 16); }
__device__ __forceinline__ float bflo(unsigned u) { return __uint_as_float(u << 16); }
__device__ __forceinline__ float bfhi(unsigned u) { return __uint_as_float(u & 0xFFFF0000u); }
__device__ __forceinline__ U16 f2bf(float f) {
  unsigned u = __float_as_uint(f);
  u += 0x7FFFu + ((u >> 16) & 1u);
  return (U16)(u >> 16);
}
__device__ __forceinline__ float ldv(const void* p, long i, bool bf) {
  return bf ? bfp((const U16*)p + i) : ((const float*)p)[i];
}

// scal slots: 0=x_mean, 1..2=walk norms (S_raw, == raw prob sums), 8..9=tension Sq, 16=bf16 flag

// ---------- init: dtype detect + x_mean + zero scalar slab ----------
__global__ __launch_bounds__(256) void init_kernel(const void* __restrict__ x, const U16* __restrict__ lng,
                                                   float* __restrict__ scal) {
  __shared__ float red[256];
  __shared__ int fl;
  int t = threadIdx.x;
  if (t == 0) fl = (lng[0] != 0) ? 1 : 0;   // ln_g==1.0: bf16 -> 0x3F80, fp32 low half -> 0x0000
  __syncthreads();
  bool bf = fl != 0;
  float s = 0.f;
  for (int i = t; i < 1024; i += 256) s += ldv(x, i, bf);
  red[t] = s; __syncthreads();
  for (int o = 128; o; o >>= 1) { if (t < o) red[t] += red[t + o]; __syncthreads(); }
  if (t == 0) { scal[0] = red[0] * (1.f / 1024.f); scal[16] = bf ? 1.f : 0.f; }
  else if (t < 64 && t != 16) scal[t] = 0.f;
}

// ---------- quantum walk: coined (adaptive raw input on iter 0; folds prev-iter norm) ----------
__global__ __launch_bounds__(256) void walk_coined_kernel(const void* __restrict__ arv, const void* __restrict__ aiv,
                                                          float* __restrict__ cr, float* __restrict__ ci,
                                                          const void* __restrict__ coinR, const void* __restrict__ coinI,
                                                          const float* __restrict__ scal, int iter) {
  bool bf = scal[16] != 0.f;
  int id = blockIdx.x * 256 + threadIdx.x;   // (n,d): 2048*1024
  int n = id >> 10, d = id & 1023;
  size_t b0 = (size_t)n * 2048 + d;
  float pre = 1.f;
  float a0r, a0i, a1r, a1i;
  if (iter == 0) {
    a0r = ldv(arv, b0, bf); a1r = ldv(arv, b0 + 1024, bf);
    a0i = ldv(aiv, b0, bf); a1i = ldv(aiv, b0 + 1024, bf);
  } else {
    pre = 1.f / (sqrtf(scal[iter]) + 1e-8f);   // norm of iteration iter-1 lives in slot iter
    const float* ar = (const float*)arv;
    const float* ai = (const float*)aiv;
    a0r = ar[b0]; a1r = ar[b0 + 1024]; a0i = ai[b0]; a1i = ai[b0 + 1024];
  }
  a0r *= pre; a0i *= pre; a1r *= pre; a1i *= pre;
  float c00r = ldv(coinR, 0, bf), c01r = ldv(coinR, 1, bf), c10r = ldv(coinR, 2, bf), c11r = ldv(coinR, 3, bf);
  float c00i = ldv(coinI, 0, bf), c01i = ldv(coinI, 1, bf), c10i = ldv(coinI, 2, bf), c11i = ldv(coinI, 3, bf);
  cr[b0]        = c00r * a0r - c00i * a0i + c01r * a1r - c01i * a1i;
  ci[b0]        = c00r * a0i + c00i * a0r + c01r * a1i + c01i * a1r;
  cr[b0 + 1024] = c10r * a0r - c10i * a0i + c11r * a1r - c11i * a1i;
  ci[b0 + 1024] = c10r * a0i + c10i * a0r + c11r * a1i + c11i * a1r;
}

// ---------- fused walk_new + inject_stats: block per node n ----------
__global__ __launch_bounds__(256) void walk_new_stats_kernel(const float* __restrict__ cr, const float* __restrict__ ci,
                                                             float* __restrict__ ar, float* __restrict__ ai,
                                                             const float* __restrict__ scal, float* __restrict__ scalw,
                                                             int slot, float* __restrict__ probs, float* __restrict__ ph) {
  __shared__ float r1[256], r2[256];
  int n = blockIdx.x, t = threadIdx.x;
  float th = scal[0] * 0.1f;
  float sn, cs; sincosf(th, &sn, &cs);
  float pacc = 0.f, phacc = 0.f;
  #pragma unroll
  for (int it = 0; it < 4; ++it) {
    int d = t + it * 256;
    size_t b0 = (size_t)n * 2048 + d;
    float n0r = cr[b0], n0i = ci[b0];
    float s1r = 0.f, s1i = 0.f;
    #pragma unroll
    for (int k = 0; k < 11; ++k) {
      size_t j = (size_t)(n ^ (1 << k)) * 2048 + 1024 + d;
      s1r += cr[j]; s1i += ci[j];
    }
    s1r *= (1.f / 11.f); s1i *= (1.f / 11.f);
    float o0r = n0r * cs - n0i * sn, o0i = n0r * sn + n0i * cs;
    float o1r = s1r * cs - s1i * sn, o1i = s1r * sn + s1i * cs;
    ar[b0] = o0r; ai[b0] = o0i; ar[b0 + 1024] = o1r; ai[b0 + 1024] = o1i;
    pacc += o0r * o0r + o0i * o0i + o1r * o1r + o1i * o1i;
    phacc += atan2f(o0i + o1i, o0r + o1r);
  }
  r1[t] = pacc; r2[t] = phacc; __syncthreads();
  for (int o = 128; o; o >>= 1) { if (t < o) { r1[t] += r1[t + o]; r2[t] += r2[t + o]; } __syncthreads(); }
  if (t == 0) { probs[n] = r1[0]; ph[n] = r2[0] * (1.f / 1024.f); atomicAdd(&scalw[slot], r1[0]); }
}

// ---------- inject ----------
__global__ __launch_bounds__(256) void inject_cells_kernel(const void* __restrict__ cellsIn, float* __restrict__ cells,
                                                           const float* __restrict__ probs,
                                                           const float* __restrict__ ph, const float* __restrict__ scal,
                                                           int wslot, int useRaw) {
  bool bf = scal[16] != 0.f;
  int id = blockIdx.x * 256 + threadIdx.x;   // 2048*512
  int c = id >> 9, d = id & 511;
  float invn = 1.f / (sqrtf(scal[wslot]) + 1e-8f);
  float inv2 = invn * invn;
  float denom = 1.f / (scal[wslot] * inv2 + 1e-8f);
  float psc = inv2 * denom;
  float p = probs[c] * psc;
  float interf = 0.f;
  #pragma unroll
  for (int j = 0; j < 6; ++j) interf += (p - probs[c ^ (1 << j)] * psc);
  interf *= 0.03f;
  float scale = 0.8f + 0.4f * p;
  float phc = ph[c] * 0.3f;
  float sn, cs; sincosf(phc, &sn, &cs);
  size_t base = (size_t)c * 1024 + d;
  float h1, h2;
  if (useRaw) { h1 = ldv(cellsIn, base, bf) * scale; h2 = ldv(cellsIn, base + 512, bf) * scale; }
  else        { h1 = cells[base] * scale;            h2 = cells[base + 512] * scale; }
  float r1 = h1 * cs - h2 * sn, r2 = h1 * sn + h2 * cs;
  cells[base]       = 0.5f * (r1 + h1) + interf;
  cells[base + 512] = 0.5f * (r2 + h2) + interf;
}

// ---------- frustration: one wave per column, rows in registers, shuffle chain ----------
__global__ __launch_bounds__(64) void frustration_kernel(float* __restrict__ cells, const void* __restrict__ fs,
                                                         const float* __restrict__ scal) {
  bool bf = scal[16] != 0.f;
  int d = blockIdx.x;      // 1024 columns
  int l = threadIdx.x;     // 64 lanes
  float s0 = ldv(fs, l, bf);
  float s1 = ldv(fs, l + 64, bf);
  float w0 = s0 * cells[(size_t)l * 1024 + d];
  float w1 = s1 * cells[(size_t)(l + 64) * 1024 + d];
  float stat0 = 0.f, stat1 = 0.f;
  #pragma unroll
  for (int b = 7; b < 10; ++b) {
    int j0 = l ^ (1 << b);
    int j1 = (l + 64) ^ (1 << b);
    stat0 += ldv(fs, j0, bf) * cells[(size_t)j0 * 1024 + d];
    stat1 += ldv(fs, j1, bf) * cells[(size_t)j1 * 1024 + d];
  }
  #pragma unroll
  for (int i = 0; i < 128; ++i) {
    const int hi = i >> 6;
    const int li = i & 63;
    float vsrc = (hi == 0) ? w0 : w1;
    float voth = (hi == 0) ? w1 : w0;
    float acc = __shfl(vsrc, li ^ 1) + __shfl(vsrc, li ^ 2) + __shfl(vsrc, li ^ 4)
              + __shfl(vsrc, li ^ 8) + __shfl(vsrc, li ^ 16) + __shfl(vsrc, li ^ 32)
              + __shfl(voth, li);
    if (l == li) {
      if (hi == 0) w0 = 0.85f * w0 + 0.015f * (acc + stat0);
      else         w1 = 0.85f * w1 + 0.015f * (acc + stat1);
    }
  }
  cells[(size_t)l * 1024 + d]        = s0 * w0;
  cells[(size_t)(l + 64) * 1024 + d] = s1 * w1;
}

// ---------- standing wave ----------
__global__ __launch_bounds__(256) void standing_kernel(float* __restrict__ cells, const int* __restrict__ stepp) {
  int id = blockIdx.x * 256 + threadIdx.x;   // 2M
  int c = id >> 10;
  float st = (float)stepp[0] * 0.15f;
  float fwd = fmodf(st, 2048.f);
  float bwd = fmodf(2048.f - st, 2048.f);
  float fi = (float)c;
  float r1 = 1.f / coshf((fi - fwd) * 0.5f);
  float r2 = 1.f / coshf((fi - bwd) * 0.5f);
  cells[id] *= (1.f + 0.03f * (r1 * r1 + r2 * r2));
}

// ---------- morphism: one wave per column, rows in registers, shuffle reduce ----------
__global__ __launch_bounds__(64) void morphism_kernel(float* __restrict__ cells, const int* __restrict__ stepp) {
  if (stepp[0] % 3 != 0) return;
  int d = blockIdx.x;        // 1024 columns
  int l = threadIdx.x;       // 64 lanes, 0..47 active
  float v = 0.f;
  if (l < 48) v = cells[(size_t)l * 1024 + d];
  for (int i = 0; i < 48; ++i) {
    float vi = __shfl(v, i);
    float x = v - vi;
    float e2 = __expf(2.f * x);
    float th = (l < 48) ? (1.f - 2.f / (e2 + 1.f)) : 0.f;
    th += __shfl_xor(th, 1);
    th += __shfl_xor(th, 2);
    th += __shfl_xor(th, 4);
    th += __shfl_xor(th, 8);
    th += __shfl_xor(th, 16);
    th += __shfl_xor(th, 32);
    if (l == i) v = 0.9f * v + (0.1f / 47.f) * th;
  }
  if (l < 48) cells[(size_t)l * 1024 + d] = v;
}

// ---------- faction ----------
__global__ __launch_bounds__(256) void faction_mean_kernel(const float* __restrict__ cells, float* __restrict__ fmean) {
  int id = blockIdx.x * 256 + threadIdx.x;   // 8*1024
  int f = id >> 10, d = id & 1023;
  float s = 0.f;
  for (int r = 0; r < 256; ++r) s += cells[(size_t)((f << 8) + r) * 1024 + d];
  fmean[id] = s * (1.f / 256.f);
}
__global__ __launch_bounds__(256) void faction_apply_kernel(float* __restrict__ cells, const float* __restrict__ fmean,
                                                            const int* __restrict__ stepp) {
  int id = blockIdx.x * 256 + threadIdx.x;   // 2M
  int c = id >> 10, d = id & 1023;
  int f = c >> 8, r = c & 255;
  float v = 0.85f * cells[id] + 0.15f * fmean[f * 1024 + d];
  if (stepp[0] > 5 && r < 64) {
    float g = 0.f;
    #pragma unroll
    for (int ff = 0; ff < 8; ++ff) g += fmean[ff * 1024 + d];
    v = 0.85f * v + 0.15f * g * 0.125f;
  }
  cells[id] = v;
}

// ---------- x projection ----------
__global__ __launch_bounds__(256) void xproj_kernel(const void* __restrict__ x, const void* __restrict__ w_in,
                                                    const void* __restrict__ b_in, float* __restrict__ xp,
                                                    const float* __restrict__ scal) {
  bool bf = scal[16] != 0.f;
  int id = blockIdx.x * 256 + threadIdx.x;   // 2048
  int b = id >> 10, o = id & 1023;
  float acc = ldv(b_in, o, bf);
  if (bf) {
    const U16* xr = (const U16*)x + b * 512;
    const U16* wr = (const U16*)w_in + (long)o * 512;
    for (int k = 0; k < 512; ++k) acc += bfp(xr + k) * bfp(wr + k);
  } else {
    const float* xr = (const float*)x + b * 512;
    const float* wr = (const float*)w_in + (long)o * 512;
    for (int k = 0; k < 512; ++k) acc += xr[k] * wr[k];
  }
  xp[id] = acc;
}

// writes fp32 cellsB + bf16 mirror
__global__ __launch_bounds__(256) void cellsB_kernel(const float* __restrict__ cells, const float* __restrict__ xp,
                                                     float* __restrict__ cellsB, U16* __restrict__ cellsB16) {
  int id = blockIdx.x * 256 + threadIdx.x;   // 4M
  int b = id >> 21;
  int cd = id & ((1 << 21) - 1);
  int d = id & 1023;
  float v = cells[cd] + 0.1f * xp[(b << 10) + d];
  cellsB[id] = v;
  cellsB16[id] = f2bf(v);
}

// ---------- MFMA GEMM: C[M,N] = A[M,1024] * W[N,1024]^T + bias ----------
// aF32: A is fp32 (staged with cvt), else bf16.
__global__ __launch_bounds__(256) void mfma_gemm_kernel(const void* __restrict__ Av, int aF32,
                                                        const void* __restrict__ Wv, long Woff,
                                                        const void* __restrict__ biasv, long Boff,
                                                        void* __restrict__ Cout, int N, int mode,
                                                        const float* __restrict__ scal) {
  __shared__ U16 Al[4096];
  __shared__ U16 Wl[4096];
  bool bf = scal[16] != 0.f;
  const int K = 1024;
  int t = threadIdx.x;
  int wv = t >> 6, l = t & 63;
  int n0 = blockIdx.x * 128, m0 = blockIdx.y * 128;
  int wmt = (wv & 1) * 4;
  int wnt = (wv >> 1) * 4;
  f32x4 acc[4][4];
  #pragma unroll
  for (int i = 0; i < 4; ++i)
    #pragma unroll
    for (int j = 0; j < 4; ++j) acc[i][j] = (f32x4){0.f, 0.f, 0.f, 0.f};
  const U16* A16 = (const U16*)Av;
  const float* Af = (const float*)Av;
  const U16* Wb = (const U16*)Wv + Woff;
  const float* Wf = (const float*)Wv + Woff;
  for (int k0 = 0; k0 < K; k0 += 32) {
    __syncthreads();
    #pragma unroll
    for (int i = 0; i < 2; ++i) {
      int f = i * 256 + t;
      int m = f >> 2, q = f & 3;
      int ldso = ((m >> 4) * 64 + q * 16 + (m & 15)) * 8;
      bf16x8 av;
      if (aF32) {
        const float* ap = Af + (size_t)(m0 + m) * K + k0 + q * 8;
        float4 a0 = *(const float4*)ap;
        float4 a1 = *(const float4*)(ap + 4);
        av[0] = (short)f2bf(a0.x); av[1] = (short)f2bf(a0.y);
        av[2] = (short)f2bf(a0.z); av[3] = (short)f2bf(a0.w);
        av[4] = (short)f2bf(a1.x); av[5] = (short)f2bf(a1.y);
        av[6] = (short)f2bf(a1.z); av[7] = (short)f2bf(a1.w);
      } else {
        av = *(const bf16x8*)(A16 + (size_t)(m0 + m) * K + k0 + q * 8);
      }
      *(bf16x8*)&Al[ldso] = av;
      bf16x8 wvv;
      if (bf) {
        wvv = *(const bf16x8*)(Wb + (size_t)(n0 + m) * K + k0 + q * 8);
      } else {
        const float* fp = Wf + (size_t)(n0 + m) * K + k0 + q * 8;
        float4 f0 = *(const float4*)fp;
        float4 f1 = *(const float4*)(fp + 4);
        wvv[0] = (short)f2bf(f0.x); wvv[1] = (short)f2bf(f0.y);
        wvv[2] = (short)f2bf(f0.z); wvv[3] = (short)f2bf(f0.w);
        wvv[4] = (short)f2bf(f1.x); wvv[5] = (short)f2bf(f1.y);
        wvv[6] = (short)f2bf(f1.z); wvv[7] = (short)f2bf(f1.w);
      }
      *(bf16x8*)&Wl[ldso] = wvv;
    }
    __syncthreads();
    bf16x8 afr[4], bfr[4];
    #pragma unroll
    for (int i = 0; i < 4; ++i) afr[i] = *(const bf16x8*)&Al[((wmt + i) * 64 + l) * 8];
    #pragma unroll
    for (int j = 0; j < 4; ++j) bfr[j] = *(const bf16x8*)&Wl[((wnt + j) * 64 + l) * 8];
    #pragma unroll
    for (int i = 0; i < 4; ++i)
      #pragma unroll
      for (int j = 0; j < 4; ++j)
        acc[i][j] = __builtin_amdgcn_mfma_f32_16x16x32_bf16(afr[i], bfr[j], acc[i][j], 0, 0, 0);
  }
  bool outBf = (mode == 1) || (mode == 2 && bf);
  int cl = l & 15, rq = l >> 4;
  #pragma unroll
  for (int j = 0; j < 4; ++j) {
    int n = n0 + (wnt + j) * 16 + cl;
    float bv = ldv(biasv, Boff + n, bf);
    #pragma unroll
    for (int i = 0; i < 4; ++i) {
      int mrow = m0 + (wmt + i) * 16 + rq * 4;
      #pragma unroll
      for (int r = 0; r < 4; ++r) {
        float v = acc[i][j][r] + bv;
        if (outBf) ((U16*)Cout)[(size_t)(mrow + r) * N + n] = f2bf(v);
        else       ((float*)Cout)[(size_t)(mrow + r) * N + n] = v;
      }
    }
  }
}

// ---------- fused pack of K and V into fragment-major streams ----------
__global__ __launch_bounds__(256) void pack_kv_kernel(const U16* __restrict__ qkv,
                                                      U16* __restrict__ Kp, U16* __restrict__ Vp) {
  __shared__ U16 tile[64][132];
  int t = threadIdx.x;
  int kc = blockIdx.x, bh = blockIdx.y;
  int b = bh >> 3, h = bh & 7;
  size_t dstB = ((size_t)bh * 32 + kc) * 8192;
  if (blockIdx.z == 0) {
    int w = t >> 6, l = t & 63;
    int l16 = l & 15, quad = l >> 4;
    #pragma unroll
    for (int fi = 0; fi < 4; ++fi) {
      int f = w * 4 + fi;
      int nt = f >> 2, kf = f & 3;
      const U16* src = qkv + ((size_t)(b * 2048 + kc * 64 + nt * 16 + l16)) * 3072 + 1024 + h * 128 + kf * 32 + quad * 8;
      *(uint4*)(Kp + dstB + (size_t)f * 512 + l * 8) = *(const uint4*)src;
    }
  } else {
    int r = t >> 2, c0 = (t & 3) * 32;
    const U16* src = qkv + ((size_t)(b * 2048 + kc * 64 + r)) * 3072 + 2048 + h * 128 + c0;
    #pragma unroll
    for (int q = 0; q < 8; ++q)
      *(ushort4*)&tile[r][c0 + q * 4] = *(const ushort4*)(src + q * 4);
    __syncthreads();
    #pragma unroll
    for (int i = 0; i < 4; ++i) {
      int p = t + 256 * i;
      int g = p >> 6, l = p & 63;
      int l16 = l & 15, quad = l >> 4;
      int nt = g >> 1, kf = g & 1;
      U16 vals[8];
      #pragma unroll
      for (int j = 0; j < 8; ++j) vals[j] = tile[kf * 32 + quad * 8 + j][nt * 16 + l16];
      *(uint4*)(Vp + dstB + (size_t)g * 512 + l * 8) = *(const uint4*)vals;
    }
  }
}

// ---------- zero z+G scratch (in d_out) ----------
__global__ __launch_bounds__(256) void zero_zg_kernel(float* __restrict__ zg) {
  int id = blockIdx.x * 256 + threadIdx.x;
  if (id < 294912) zg[id] = 0.f;
}

// ---------- MFMA fused attention, k-split (khalf of 2), partial outputs ----------
// zg[0..32768): z partials per (m=b*2048+q)*8+h  (atomicAdd)
// zg[32768..294912): Gram partials per m*64+h1*8+h2 (atomicAdd)
// half0 O -> O32a (plain f32); half1 O -> dead K/V stripes of qkv rows (plain f32)
#define ATT_WST 1032   // e-LDS wave-region stride (U16)
__global__ __launch_bounds__(512, 2) void attn_mfma_kernel(U16* __restrict__ qkv,
                                                           const U16* __restrict__ Kp, const U16* __restrict__ Vp,
                                                           float* __restrict__ O32a,
                                                           float* __restrict__ zg) {
  __shared__ U16 ebuf[2 * 8 * ATT_WST];
  int t = threadIdx.x;
  int w = t >> 6;          // head
  int l = t & 63;
  int l16 = l & 15, quad = l >> 4;
  int idx = blockIdx.x;
  int khalf = idx & 1;
  int b = (idx >> 1) & 1;
  int q0 = (idx >> 2) * 16;
  size_t rowB = (size_t)b * 2048;
  const float sc = 0.08838834764831845f;
  const int c0 = khalf * 16;

  // Q A-frags: A[m=q=l16][d=kf*32+quad*8+j]
  bf16x8 afr[4];
  const U16* Qbase = qkv + (rowB + q0 + l16) * 3072 + w * 128 + quad * 8;
  #pragma unroll
  for (int kf = 0; kf < 4; ++kf) afr[kf] = *(const bf16x8*)(Qbase + kf * 32);

  f32x4 oacc[8];
  #pragma unroll
  for (int i = 0; i < 8; ++i) oacc[i] = (f32x4){0.f, 0.f, 0.f, 0.f};
  f32x4 gacc = (f32x4){0.f, 0.f, 0.f, 0.f};
  float zacc[4] = {0.f, 0.f, 0.f, 0.f};

  const U16* KpB = Kp + (size_t)(b * 8 + w) * 262144;   // 32 chunks * 8192
  const U16* VpB = Vp + (size_t)(b * 8 + w) * 262144;

  // register-resident K and V fragment buffers (preload chunk c0)
  bf16x8 bK[4][4];   // 64 VGPR
  bf16x8 bV[8][2];   // 64 VGPR
  #pragma unroll
  for (int nt = 0; nt < 4; ++nt)
    #pragma unroll
    for (int kf = 0; kf < 4; ++kf)
      bK[nt][kf] = *(const bf16x8*)(KpB + (size_t)c0 * 8192 + (size_t)(nt * 4 + kf) * 512 + l * 8);
  #pragma unroll
  for (int nt = 0; nt < 8; ++nt)
    #pragma unroll
    for (int kf = 0; kf < 2; ++kf)
      bV[nt][kf] = *(const bf16x8*)(VpB + (size_t)c0 * 8192 + (size_t)(nt * 2 + kf) * 512 + l * 8);

  for (int kc = c0; kc < c0 + 16; ++kc) {
    // QK^T
    f32x4 sacc[4];
    #pragma unroll
    for (int nt = 0; nt < 4; ++nt) {
      sacc[nt] = (f32x4){0.f, 0.f, 0.f, 0.f};
      #pragma unroll
      for (int kf = 0; kf < 4; ++kf)
        sacc[nt] = __builtin_amdgcn_mfma_f32_16x16x32_bf16(afr[kf], bK[nt][kf], sacc[nt], 0, 0, 0);
    }
    // exp + z-accum + e store (frag-major per wave region)
    U16* eb = &ebuf[(kc & 1) * 8 * ATT_WST + w * ATT_WST];
    #pragma unroll
    for (int nt = 0; nt < 4; ++nt) {
      int kq = nt * 2 + (l16 >> 3);
      int j = l16 & 7;
      #pragma unroll
      for (int r = 0; r < 4; ++r) {
        float e = __expf(fminf(sacc[nt][r] * sc, 30.f));
        zacc[r] += e;
        eb[kq * 128 + (quad * 4 + r) * 8 + j] = f2bf(e);
      }
    }
    __syncthreads();
    // prefetch next-chunk K AFTER barrier (bK consumed by QK above)
    if (kc < c0 + 15) {
      const U16* Kc = KpB + (size_t)(kc + 1) * 8192;
      #pragma unroll
      for (int nt = 0; nt < 4; ++nt)
        #pragma unroll
        for (int kf = 0; kf < 4; ++kf)
          bK[nt][kf] = *(const bf16x8*)(Kc + (size_t)(nt * 4 + kf) * 512 + l * 8);
    }
    // PV: A = own-head e from LDS (lane*16B), B = register-resident bV
    #pragma unroll
    for (int kf = 0; kf < 2; ++kf) {
      bf16x8 pfr = *(const bf16x8*)&eb[kf * 512 + l * 8];
      #pragma unroll
      for (int nt = 0; nt < 8; ++nt)
        oacc[nt] = __builtin_amdgcn_mfma_f32_16x16x32_bf16(pfr, bV[nt][kf], oacc[nt], 0, 0, 0);
    }
    // prefetch next-chunk V AFTER PV consumed bV
    if (kc < c0 + 15) {
      const U16* Vc = VpB + (size_t)(kc + 1) * 8192;
      #pragma unroll
      for (int nt = 0; nt < 8; ++nt)
        #pragma unroll
        for (int kf = 0; kf < 2; ++kf)
          bV[nt][kf] = *(const bf16x8*)(Vc + (size_t)(nt * 2 + kf) * 512 + l * 8);
    }
    // Gram: A=B=e-frag with m=(h' + 8*q-parity), q-pair = w
    {
      const U16* gb = &ebuf[(kc & 1) * 8 * ATT_WST];
      #pragma unroll
      for (int kf = 0; kf < 2; ++kf) {
        bf16x8 gfr = *(const bf16x8*)(gb + (size_t)(l & 7) * ATT_WST + kf * 512
                                      + (quad * 16 + w * 2 + ((l >> 3) & 1)) * 8);
        gacc = __builtin_amdgcn_mfma_f32_16x16x32_bf16(gfr, gfr, gacc, 0, 0, 0);
      }
    }
  }
  // Z reduce (butterfly over 16 k-columns) + atomic into zg
  #pragma unroll
  for (int r = 0; r < 4; ++r) {
    float z = zacc[r];
    z += __shfl_xor(z, 1); z += __shfl_xor(z, 2);
    z += __shfl_xor(z, 4); z += __shfl_xor(z, 8);
    zacc[r] = z;
  }
  if (l16 == 0) {
    #pragma unroll
    for (int r = 0; r < 4; ++r) {
      size_t m = rowB + q0 + quad * 4 + r;
      atomicAdd(&zg[m * 8 + w], zacc[r]);
    }
  }
  // O partial store (unnormalized f32)
  #pragma unroll
  for (int r = 0; r < 4; ++r) {
    int q = quad * 4 + r;
    size_t m = rowB + q0 + q;
    float* orow;
    if (khalf == 0) orow = O32a + m * 1024 + w * 128 + l16;
    else            orow = (float*)(qkv + m * 3072 + 1024) + w * 128 + l16;   // dead K/V stripe
    #pragma unroll
    for (int nt = 0; nt < 8; ++nt) orow[nt * 16] = oacc[nt][r];
  }
  // Gram partial: valid entries have m-parity == n-parity
  {
    int h2 = l16 & 7, b2 = l16 >> 3;
    int a = quad >> 1;
    if (a == b2) {
      int q = w * 2 + a;
      size_t m = rowB + q0 + q;
      float* G = zg + 32768;
      #pragma unroll
      for (int r = 0; r < 4; ++r) {
        int h1 = (quad * 4 + r) & 7;
        atomicAdd(&G[m * 64 + h1 * 8 + h2], gacc[r]);
      }
    }
  }
}

// ---------- combine O halves + normalize by total z (in-place into O32a, f32) ----------
__global__ __launch_bounds__(256) void attn_norm_kernel(float* __restrict__ O32a, const U16* __restrict__ qkv,
                                                        const float* __restrict__ zg) {
  int id = blockIdx.x * 256 + threadIdx.x;   // 1048576 threads * 4 f32
  int base = id * 4;
  int m = base >> 10, d = base & 1023;
  const float* ob = (const float*)(qkv + (size_t)m * 3072 + 1024);
  float4 a = *(const float4*)&O32a[base];
  float4 bv = *(const float4*)&ob[d];
  float inv = 1.f / zg[m * 8 + (d >> 7)];
  a.x = (a.x + bv.x) * inv;
  a.y = (a.y + bv.y) * inv;
  a.z = (a.z + bv.z) * inv;
  a.w = (a.w + bv.w) * inv;
  *(float4*)&O32a[base] = a;
}

// ---------- gram finalize: sum G/(z1*z2)/64 - 2 into scal[slot] ----------
__global__ __launch_bounds__(256) void gram_fin_kernel(const float* __restrict__ zg, float* __restrict__ scal, int slot) {
  __shared__ float red[256];
  int t = threadIdx.x;
  const float* G = zg + 32768;
  float s = 0.f;
  for (int i = blockIdx.x * 256 * 16 + t; i < (blockIdx.x + 1) * 256 * 16; i += 256) {
    int m = i >> 6, h1 = (i >> 3) & 7, h2 = i & 7;
    s += G[i] / (zg[m * 8 + h1] * zg[m * 8 + h2]);
  }
  red[t] = s; __syncthreads();
  for (int o = 128; o; o >>= 1) { if (t < o) red[t] += red[t + o]; __syncthreads(); }
  if (t == 0) atomicAdd(&scal[slot], red[0] * (1.f / 64.f) - (blockIdx.x == 0 ? 2.0f : 0.0f));
}

// ---------- residual + LayerNorm (writes fp32 + bf16 mirror) ----------
__global__ __launch_bounds__(256) void ln_kernel(float* __restrict__ cellsB, U16* __restrict__ cellsB16,
                                                 const float* __restrict__ proj,
                                                 const void* __restrict__ gv, const void* __restrict__ bv, long off,
                                                 const float* __restrict__ scal) {
  __shared__ float red[256];
  bool bf = scal[16] != 0.f;
  int row = blockIdx.x, t = threadIdx.x;
  size_t base = (size_t)row * 1024;
  int d = 4 * t;
  float4 cv = *(const float4*)&cellsB[base + d];
  float4 pv = *(const float4*)&proj[base + d];
  float v0 = cv.x + pv.x, v1 = cv.y + pv.y, v2 = cv.z + pv.z, v3 = cv.w + pv.w;
  red[t] = v0 + v1 + v2 + v3; __syncthreads();
  for (int o = 128; o; o >>= 1) { if (t < o) red[t] += red[t + o]; __syncthreads(); }
  float mu = red[0] * (1.f / 1024.f);
  __syncthreads();
  float d0 = v0 - mu, d1 = v1 - mu, d2 = v2 - mu, d3 = v3 - mu;
  red[t] = d0 * d0 + d1 * d1 + d2 * d2 + d3 * d3; __syncthreads();
  for (int o = 128; o; o >>= 1) { if (t < o) red[t] += red[t + o]; __syncthreads(); }
  float rstd = rsqrtf(red[0] * (1.f / 1024.f) + 1e-5f);
  float4 out;
  out.x = d0 * rstd * ldv(gv, off + d, bf)     + ldv(bv, off + d, bf);
  out.y = d1 * rstd * ldv(gv, off + d + 1, bf) + ldv(bv, off + d + 1, bf);
  out.z = d2 * rstd * ldv(gv, off + d + 2, bf) + ldv(bv, off + d + 2, bf);
  out.w = d3 * rstd * ldv(gv, off + d + 3, bf) + ldv(bv, off + d + 3, bf);
  *(float4*)&cellsB[base + d] = out;
  ushort4 ob;
  ob.x = f2bf(out.x); ob.y = f2bf(out.y); ob.z = f2bf(out.z); ob.w = f2bf(out.w);
  *(ushort4*)&cellsB16[base + d] = ob;
}

// ---------- tension finalize ----------
__global__ void tension_kernel(const float* __restrict__ scal, void* __restrict__ out) {
  bool bf = scal[16] != 0.f;
  float cnt = 8388608.f;
  float ten = 0.f;
  for (int l = 0; l < 2; ++l) {
    float v = scal[8 + l] / (cnt - 1.f);
    ten += sqrtf(fmaxf(v, 0.f));
  }
  ten *= 0.5f;
  if (bf) ((U16*)out)[2097152] = f2bf(ten);
  else    ((float*)out)[2097152] = ten;
}

extern "C" void kernel_launch(void* const* d_in, const int* in_sizes, int n_in,
                              void* d_out, int out_size, void* d_ws, size_t ws_size,
                              hipStream_t stream) {
  const void* X    = d_in[0];
  const void* AR   = d_in[1];
  const void* AI   = d_in[2];
  const void* CRc  = d_in[3];
  const void* CIc  = d_in[4];
  const void* CE   = d_in[5];
  const void* FS   = d_in[6];
  const void* WIN  = d_in[7];
  const void* BIN  = d_in[8];
  const void* AIW  = d_in[9];
  const void* AIB  = d_in[10];
  const void* AOW  = d_in[11];
  const void* AOB  = d_in[12];
  const void* LNG  = d_in[13];
  const void* LNB  = d_in[14];
  const void* WOUT = d_in[15];
  const void* BOUT = d_in[16];
  const int* STEP  = (const int*)d_in[17];

  // ws layout (float offsets), total ~75.6 MB (unchanged)
  float* ws = (float*)d_ws;
  float* scal  = ws;                  // 64
  float* probs = ws + 64;
  float* ph    = ws + 64 + 2048;
  float* fmean = ws + 64 + 4096;
  float* xp    = ws + 64 + 12288;
  float* cells = ws + 16384;           // 2M f (dead after cellsB_kernel -> reused as Vp)
  float* CB    = ws + 16384 + 2097152; // 16.78M f region
  // phase 1:
  float* ar = CB;
  float* ai = CB + 4194304;
  float* cr = CB + 8388608;
  float* ci = CB + 12582912;
  // phase 2 (aliases phase 1):
  float* cellsB   = CB;                                   // [0 .. 4M)
  U16*   qkv16    = (U16*)(CB + 4194304);                 // [4M .. 10.49M) x U16; K/V stripes dead after pack -> O32b
  float* proj     = CB + 4194304;                         // aliases dead qkv
  float* O32a     = CB + 10485760;                        // [10.49 .. 14.68M) f32 partial/final O (attnO16+cellsB16 regions)
  U16*   cellsB16 = (U16*)(CB + 12582912);                // rebuilt by ln each layer
  U16*   Kp       = (U16*)(CB + 14680064);                // [14.68 .. 16.78M) = 4M U16
  U16*   Vp       = (U16*)cells;                          // cells region dead in phase 2: 4M U16
  float* zg       = (float*)d_out;                        // scratch: z[32768] + G[262144] (overwritten by final gemm)

  init_kernel<<<1, 256, 0, stream>>>(X, (const U16*)LNG, scal);

  for (int w = 0; w < 2; ++w) {
    if (w == 0) walk_coined_kernel<<<8192, 256, 0, stream>>>(AR, AI, cr, ci, CRc, CIc, scal, 0);
    else        walk_coined_kernel<<<8192, 256, 0, stream>>>(ar, ai, cr, ci, CRc, CIc, scal, 1);
    walk_new_stats_kernel<<<2048, 256, 0, stream>>>(cr, ci, ar, ai, scal, scal, 1 + w, probs, ph);
    inject_cells_kernel<<<4096, 256, 0, stream>>>(w == 0 ? CE : (const void*)cells, cells,
                                                  probs, ph, scal, 1 + w, w == 0 ? 1 : 0);
  }
  frustration_kernel<<<1024, 64, 0, stream>>>(cells, FS, scal);
  standing_kernel<<<8192, 256, 0, stream>>>(cells, STEP);
  morphism_kernel<<<1024, 64, 0, stream>>>(cells, STEP);
  faction_mean_kernel<<<32, 256, 0, stream>>>(cells, fmean);
  faction_apply_kernel<<<8192, 256, 0, stream>>>(cells, fmean, STEP);

  xproj_kernel<<<8, 256, 0, stream>>>(X, WIN, BIN, xp, scal);
  cellsB_kernel<<<16384, 256, 0, stream>>>(cells, xp, cellsB, cellsB16);
  // cells region now dead -> Vp

  for (int l = 0; l < 2; ++l) {
    mfma_gemm_kernel<<<dim3(24, 32), 256, 0, stream>>>(cellsB16, 0, AIW, (long)l * 3072 * 1024,
                                                       AIB, (long)l * 3072, qkv16, 3072, 1, scal);
    pack_kv_kernel<<<dim3(32, 16, 2), 256, 0, stream>>>(qkv16, Kp, Vp);
    zero_zg_kernel<<<1152, 256, 0, stream>>>(zg);
    attn_mfma_kernel<<<512, 512, 0, stream>>>(qkv16, Kp, Vp, O32a, zg);
    attn_norm_kernel<<<4096, 256, 0, stream>>>(O32a, qkv16, zg);
    gram_fin_kernel<<<64, 256, 0, stream>>>(zg, scal, 8 + l);
    mfma_gemm_kernel<<<dim3(8, 32), 256, 0, stream>>>(O32a, 1, AOW, (long)l * 1024 * 1024,
                                                      AOB, (long)l * 1024, proj, 1024, 0, scal);
    ln_kernel<<<4096, 256, 0, stream>>>(cellsB, cellsB16, proj, LNG, LNB, (long)l * 1024, scal);
  }
  mfma_gemm_kernel<<<dim3(4, 32), 256, 0, stream>>>(cellsB16, 0, WOUT, 0, BOUT, 0, d_out, 512, 2, scal);
  tension_kernel<<<1, 1, 0, stream>>>(scal, d_out);
}

// Round 4
// 915.657 us; speedup vs baseline: 1.0896x; 1.0896x over previous
//
#include <hip/hip_runtime.h>

#define U16 unsigned short

typedef short bf16x8 __attribute__((ext_vector_type(8)));
typedef float f32x4 __attribute__((ext_vector_type(4)));

// ---------- bf16 helpers ----------
__device__ __forceinline__ float bfp(const U16* p) { return __uint_as_float(((unsigned)(*p)) << 16); }
__device__ __forceinline__ U16 f2bf(float f) {
  unsigned u = __float_as_uint(f);
  u += 0x7FFFu + ((u >> 16) & 1u);
  return (U16)(u >> 16);
}
__device__ __forceinline__ float ldv(const void* p, long i, bool bf) {
  return bf ? bfp((const U16*)p + i) : ((const float*)p)[i];
}

// scal slots: 0=x_mean, 1..2=walk norms (S_raw, == raw prob sums), 8..9=tension Sq, 16=bf16 flag

// ---------- init: dtype detect + x_mean + zero scalar slab ----------
__global__ __launch_bounds__(256) void init_kernel(const void* __restrict__ x, const U16* __restrict__ lng,
                                                   float* __restrict__ scal) {
  __shared__ float red[256];
  __shared__ int fl;
  int t = threadIdx.x;
  if (t == 0) fl = (lng[0] != 0) ? 1 : 0;   // ln_g==1.0: bf16 -> 0x3F80, fp32 low half -> 0x0000
  __syncthreads();
  bool bf = fl != 0;
  float s = 0.f;
  for (int i = t; i < 1024; i += 256) s += ldv(x, i, bf);
  red[t] = s; __syncthreads();
  for (int o = 128; o; o >>= 1) { if (t < o) red[t] += red[t + o]; __syncthreads(); }
  if (t == 0) { scal[0] = red[0] * (1.f / 1024.f); scal[16] = bf ? 1.f : 0.f; }
  else if (t < 64 && t != 16) scal[t] = 0.f;
}

// ---------- quantum walk: coined ----------
__global__ __launch_bounds__(256) void walk_coined_kernel(const void* __restrict__ arv, const void* __restrict__ aiv,
                                                          float* __restrict__ cr, float* __restrict__ ci,
                                                          const void* __restrict__ coinR, const void* __restrict__ coinI,
                                                          const float* __restrict__ scal, int iter) {
  bool bf = scal[16] != 0.f;
  int id = blockIdx.x * 256 + threadIdx.x;   // (n,d): 2048*1024
  int n = id >> 10, d = id & 1023;
  size_t b0 = (size_t)n * 2048 + d;
  float pre = 1.f;
  float a0r, a0i, a1r, a1i;
  if (iter == 0) {
    a0r = ldv(arv, b0, bf); a1r = ldv(arv, b0 + 1024, bf);
    a0i = ldv(aiv, b0, bf); a1i = ldv(aiv, b0 + 1024, bf);
  } else {
    pre = 1.f / (sqrtf(scal[iter]) + 1e-8f);
    const float* ar = (const float*)arv;
    const float* ai = (const float*)aiv;
    a0r = ar[b0]; a1r = ar[b0 + 1024]; a0i = ai[b0]; a1i = ai[b0 + 1024];
  }
  a0r *= pre; a0i *= pre; a1r *= pre; a1i *= pre;
  float c00r = ldv(coinR, 0, bf), c01r = ldv(coinR, 1, bf), c10r = ldv(coinR, 2, bf), c11r = ldv(coinR, 3, bf);
  float c00i = ldv(coinI, 0, bf), c01i = ldv(coinI, 1, bf), c10i = ldv(coinI, 2, bf), c11i = ldv(coinI, 3, bf);
  cr[b0]        = c00r * a0r - c00i * a0i + c01r * a1r - c01i * a1i;
  ci[b0]        = c00r * a0i + c00i * a0r + c01r * a1i + c01i * a1r;
  cr[b0 + 1024] = c10r * a0r - c10i * a0i + c11r * a1r - c11i * a1i;
  ci[b0 + 1024] = c10r * a0i + c10i * a0r + c11r * a1i + c11i * a1r;
}

// ---------- fused walk_new + inject_stats ----------
__global__ __launch_bounds__(256) void walk_new_stats_kernel(const float* __restrict__ cr, const float* __restrict__ ci,
                                                             float* __restrict__ ar, float* __restrict__ ai,
                                                             const float* __restrict__ scal, float* __restrict__ scalw,
                                                             int slot, float* __restrict__ probs, float* __restrict__ ph) {
  __shared__ float r1[256], r2[256];
  int n = blockIdx.x, t = threadIdx.x;
  float th = scal[0] * 0.1f;
  float sn, cs; sincosf(th, &sn, &cs);
  float pacc = 0.f, phacc = 0.f;
  #pragma unroll
  for (int it = 0; it < 4; ++it) {
    int d = t + it * 256;
    size_t b0 = (size_t)n * 2048 + d;
    float n0r = cr[b0], n0i = ci[b0];
    float s1r = 0.f, s1i = 0.f;
    #pragma unroll
    for (int k = 0; k < 11; ++k) {
      size_t j = (size_t)(n ^ (1 << k)) * 2048 + 1024 + d;
      s1r += cr[j]; s1i += ci[j];
    }
    s1r *= (1.f / 11.f); s1i *= (1.f / 11.f);
    float o0r = n0r * cs - n0i * sn, o0i = n0r * sn + n0i * cs;
    float o1r = s1r * cs - s1i * sn, o1i = s1r * sn + s1i * cs;
    ar[b0] = o0r; ai[b0] = o0i; ar[b0 + 1024] = o1r; ai[b0 + 1024] = o1i;
    pacc += o0r * o0r + o0i * o0i + o1r * o1r + o1i * o1i;
    phacc += atan2f(o0i + o1i, o0r + o1r);
  }
  r1[t] = pacc; r2[t] = phacc; __syncthreads();
  for (int o = 128; o; o >>= 1) { if (t < o) { r1[t] += r1[t + o]; r2[t] += r2[t + o]; } __syncthreads(); }
  if (t == 0) { probs[n] = r1[0]; ph[n] = r2[0] * (1.f / 1024.f); atomicAdd(&scalw[slot], r1[0]); }
}

// ---------- inject ----------
__global__ __launch_bounds__(256) void inject_cells_kernel(const void* __restrict__ cellsIn, float* __restrict__ cells,
                                                           const float* __restrict__ probs,
                                                           const float* __restrict__ ph, const float* __restrict__ scal,
                                                           int wslot, int useRaw) {
  bool bf = scal[16] != 0.f;
  int id = blockIdx.x * 256 + threadIdx.x;   // 2048*512
  int c = id >> 9, d = id & 511;
  float invn = 1.f / (sqrtf(scal[wslot]) + 1e-8f);
  float inv2 = invn * invn;
  float denom = 1.f / (scal[wslot] * inv2 + 1e-8f);
  float psc = inv2 * denom;
  float p = probs[c] * psc;
  float interf = 0.f;
  #pragma unroll
  for (int j = 0; j < 6; ++j) interf += (p - probs[c ^ (1 << j)] * psc);
  interf *= 0.03f;
  float scale = 0.8f + 0.4f * p;
  float phc = ph[c] * 0.3f;
  float sn, cs; sincosf(phc, &sn, &cs);
  size_t base = (size_t)c * 1024 + d;
  float h1, h2;
  if (useRaw) { h1 = ldv(cellsIn, base, bf) * scale; h2 = ldv(cellsIn, base + 512, bf) * scale; }
  else        { h1 = cells[base] * scale;            h2 = cells[base + 512] * scale; }
  float r1 = h1 * cs - h2 * sn, r2 = h1 * sn + h2 * cs;
  cells[base]       = 0.5f * (r1 + h1) + interf;
  cells[base + 512] = 0.5f * (r2 + h2) + interf;
}

// ---------- frustration: one wave per column, rows in registers, shuffle chain ----------
__global__ __launch_bounds__(64) void frustration_kernel(float* __restrict__ cells, const void* __restrict__ fs,
                                                         const float* __restrict__ scal) {
  bool bf = scal[16] != 0.f;
  int d = blockIdx.x;      // 1024 columns
  int l = threadIdx.x;     // 64 lanes
  float s0 = ldv(fs, l, bf);
  float s1 = ldv(fs, l + 64, bf);
  float w0 = s0 * cells[(size_t)l * 1024 + d];
  float w1 = s1 * cells[(size_t)(l + 64) * 1024 + d];
  float stat0 = 0.f, stat1 = 0.f;
  #pragma unroll
  for (int b = 7; b < 10; ++b) {
    int j0 = l ^ (1 << b);
    int j1 = (l + 64) ^ (1 << b);
    stat0 += ldv(fs, j0, bf) * cells[(size_t)j0 * 1024 + d];
    stat1 += ldv(fs, j1, bf) * cells[(size_t)j1 * 1024 + d];
  }
  #pragma unroll
  for (int i = 0; i < 128; ++i) {
    const int hi = i >> 6;
    const int li = i & 63;
    float vsrc = (hi == 0) ? w0 : w1;
    float voth = (hi == 0) ? w1 : w0;
    float acc = __shfl(vsrc, li ^ 1) + __shfl(vsrc, li ^ 2) + __shfl(vsrc, li ^ 4)
              + __shfl(vsrc, li ^ 8) + __shfl(vsrc, li ^ 16) + __shfl(vsrc, li ^ 32)
              + __shfl(voth, li);
    if (l == li) {
      if (hi == 0) w0 = 0.85f * w0 + 0.015f * (acc + stat0);
      else         w1 = 0.85f * w1 + 0.015f * (acc + stat1);
    }
  }
  cells[(size_t)l * 1024 + d]        = s0 * w0;
  cells[(size_t)(l + 64) * 1024 + d] = s1 * w1;
}

// ---------- standing wave ----------
__global__ __launch_bounds__(256) void standing_kernel(float* __restrict__ cells, const int* __restrict__ stepp) {
  int id = blockIdx.x * 256 + threadIdx.x;   // 2M
  int c = id >> 10;
  float st = (float)stepp[0] * 0.15f;
  float fwd = fmodf(st, 2048.f);
  float bwd = fmodf(2048.f - st, 2048.f);
  float fi = (float)c;
  float r1 = 1.f / coshf((fi - fwd) * 0.5f);
  float r2 = 1.f / coshf((fi - bwd) * 0.5f);
  cells[id] *= (1.f + 0.03f * (r1 * r1 + r2 * r2));
}

// ---------- morphism: one wave per column, rows in registers, shuffle reduce ----------
__global__ __launch_bounds__(64) void morphism_kernel(float* __restrict__ cells, const int* __restrict__ stepp) {
  if (stepp[0] % 3 != 0) return;
  int d = blockIdx.x;        // 1024 columns
  int l = threadIdx.x;       // 64 lanes, 0..47 active
  float v = 0.f;
  if (l < 48) v = cells[(size_t)l * 1024 + d];
  for (int i = 0; i < 48; ++i) {
    float vi = __shfl(v, i);
    float x = v - vi;
    float e2 = __expf(2.f * x);
    float th = (l < 48) ? (1.f - 2.f / (e2 + 1.f)) : 0.f;
    th += __shfl_xor(th, 1);
    th += __shfl_xor(th, 2);
    th += __shfl_xor(th, 4);
    th += __shfl_xor(th, 8);
    th += __shfl_xor(th, 16);
    th += __shfl_xor(th, 32);
    if (l == i) v = 0.9f * v + (0.1f / 47.f) * th;
  }
  if (l < 48) cells[(size_t)l * 1024 + d] = v;
}

// ---------- faction ----------
__global__ __launch_bounds__(256) void faction_mean_kernel(const float* __restrict__ cells, float* __restrict__ fmean) {
  int id = blockIdx.x * 256 + threadIdx.x;   // 8*1024
  int f = id >> 10, d = id & 1023;
  float s = 0.f;
  for (int r = 0; r < 256; ++r) s += cells[(size_t)((f << 8) + r) * 1024 + d];
  fmean[id] = s * (1.f / 256.f);
}
__global__ __launch_bounds__(256) void faction_apply_kernel(float* __restrict__ cells, const float* __restrict__ fmean,
                                                            const int* __restrict__ stepp) {
  int id = blockIdx.x * 256 + threadIdx.x;   // 2M
  int c = id >> 10, d = id & 1023;
  int f = c >> 8, r = c & 255;
  float v = 0.85f * cells[id] + 0.15f * fmean[f * 1024 + d];
  if (stepp[0] > 5 && r < 64) {
    float g = 0.f;
    #pragma unroll
    for (int ff = 0; ff < 8; ++ff) g += fmean[ff * 1024 + d];
    v = 0.85f * v + 0.15f * g * 0.125f;
  }
  cells[id] = v;
}

// ---------- x projection ----------
__global__ __launch_bounds__(256) void xproj_kernel(const void* __restrict__ x, const void* __restrict__ w_in,
                                                    const void* __restrict__ b_in, float* __restrict__ xp,
                                                    const float* __restrict__ scal) {
  bool bf = scal[16] != 0.f;
  int id = blockIdx.x * 256 + threadIdx.x;   // 2048
  int b = id >> 10, o = id & 1023;
  float acc = ldv(b_in, o, bf);
  if (bf) {
    const U16* xr = (const U16*)x + b * 512;
    const U16* wr = (const U16*)w_in + (long)o * 512;
    for (int k = 0; k < 512; ++k) acc += bfp(xr + k) * bfp(wr + k);
  } else {
    const float* xr = (const float*)x + b * 512;
    const float* wr = (const float*)w_in + (long)o * 512;
    for (int k = 0; k < 512; ++k) acc += xr[k] * wr[k];
  }
  xp[id] = acc;
}

// writes fp32 cellsB + bf16 mirror
__global__ __launch_bounds__(256) void cellsB_kernel(const float* __restrict__ cells, const float* __restrict__ xp,
                                                     float* __restrict__ cellsB, U16* __restrict__ cellsB16) {
  int id = blockIdx.x * 256 + threadIdx.x;   // 4M
  int b = id >> 21;
  int cd = id & ((1 << 21) - 1);
  int d = id & 1023;
  float v = cells[cd] + 0.1f * xp[(b << 10) + d];
  cellsB[id] = v;
  cellsB16[id] = f2bf(v);
}

// ---------- MFMA GEMM: C[M,N] = A[M,1024] * W[N,1024]^T + bias ----------
__global__ __launch_bounds__(256) void mfma_gemm_kernel(const void* __restrict__ Av, int aF32,
                                                        const void* __restrict__ Wv, long Woff,
                                                        const void* __restrict__ biasv, long Boff,
                                                        void* __restrict__ Cout, int N, int mode,
                                                        const float* __restrict__ scal) {
  __shared__ U16 Al[4096];
  __shared__ U16 Wl[4096];
  bool bf = scal[16] != 0.f;
  const int K = 1024;
  int t = threadIdx.x;
  int wv = t >> 6, l = t & 63;
  int n0 = blockIdx.x * 128, m0 = blockIdx.y * 128;
  int wmt = (wv & 1) * 4;
  int wnt = (wv >> 1) * 4;
  f32x4 acc[4][4];
  #pragma unroll
  for (int i = 0; i < 4; ++i)
    #pragma unroll
    for (int j = 0; j < 4; ++j) acc[i][j] = (f32x4){0.f, 0.f, 0.f, 0.f};
  const U16* A16 = (const U16*)Av;
  const float* Af = (const float*)Av;
  const U16* Wb = (const U16*)Wv + Woff;
  const float* Wf = (const float*)Wv + Woff;
  for (int k0 = 0; k0 < K; k0 += 32) {
    __syncthreads();
    #pragma unroll
    for (int i = 0; i < 2; ++i) {
      int f = i * 256 + t;
      int m = f >> 2, q = f & 3;
      int ldso = ((m >> 4) * 64 + q * 16 + (m & 15)) * 8;
      bf16x8 av;
      if (aF32) {
        const float* ap = Af + (size_t)(m0 + m) * K + k0 + q * 8;
        float4 a0 = *(const float4*)ap;
        float4 a1 = *(const float4*)(ap + 4);
        av[0] = (short)f2bf(a0.x); av[1] = (short)f2bf(a0.y);
        av[2] = (short)f2bf(a0.z); av[3] = (short)f2bf(a0.w);
        av[4] = (short)f2bf(a1.x); av[5] = (short)f2bf(a1.y);
        av[6] = (short)f2bf(a1.z); av[7] = (short)f2bf(a1.w);
      } else {
        av = *(const bf16x8*)(A16 + (size_t)(m0 + m) * K + k0 + q * 8);
      }
      *(bf16x8*)&Al[ldso] = av;
      bf16x8 wvv;
      if (bf) {
        wvv = *(const bf16x8*)(Wb + (size_t)(n0 + m) * K + k0 + q * 8);
      } else {
        const float* fp = Wf + (size_t)(n0 + m) * K + k0 + q * 8;
        float4 f0 = *(const float4*)fp;
        float4 f1 = *(const float4*)(fp + 4);
        wvv[0] = (short)f2bf(f0.x); wvv[1] = (short)f2bf(f0.y);
        wvv[2] = (short)f2bf(f0.z); wvv[3] = (short)f2bf(f0.w);
        wvv[4] = (short)f2bf(f1.x); wvv[5] = (short)f2bf(f1.y);
        wvv[6] = (short)f2bf(f1.z); wvv[7] = (short)f2bf(f1.w);
      }
      *(bf16x8*)&Wl[ldso] = wvv;
    }
    __syncthreads();
    bf16x8 afr[4], bfr[4];
    #pragma unroll
    for (int i = 0; i < 4; ++i) afr[i] = *(const bf16x8*)&Al[((wmt + i) * 64 + l) * 8];
    #pragma unroll
    for (int j = 0; j < 4; ++j) bfr[j] = *(const bf16x8*)&Wl[((wnt + j) * 64 + l) * 8];
    #pragma unroll
    for (int i = 0; i < 4; ++i)
      #pragma unroll
      for (int j = 0; j < 4; ++j)
        acc[i][j] = __builtin_amdgcn_mfma_f32_16x16x32_bf16(afr[i], bfr[j], acc[i][j], 0, 0, 0);
  }
  bool outBf = (mode == 1) || (mode == 2 && bf);
  int cl = l & 15, rq = l >> 4;
  #pragma unroll
  for (int j = 0; j < 4; ++j) {
    int n = n0 + (wnt + j) * 16 + cl;
    float bv = ldv(biasv, Boff + n, bf);
    #pragma unroll
    for (int i = 0; i < 4; ++i) {
      int mrow = m0 + (wmt + i) * 16 + rq * 4;
      #pragma unroll
      for (int r = 0; r < 4; ++r) {
        float v = acc[i][j][r] + bv;
        if (outBf) ((U16*)Cout)[(size_t)(mrow + r) * N + n] = f2bf(v);
        else       ((float*)Cout)[(size_t)(mrow + r) * N + n] = v;
      }
    }
  }
}

// ---------- fused pack of K and V into fragment-major streams ----------
__global__ __launch_bounds__(256) void pack_kv_kernel(const U16* __restrict__ qkv,
                                                      U16* __restrict__ Kp, U16* __restrict__ Vp) {
  __shared__ U16 tile[64][132];
  int t = threadIdx.x;
  int kc = blockIdx.x, bh = blockIdx.y;
  int b = bh >> 3, h = bh & 7;
  size_t dstB = ((size_t)bh * 32 + kc) * 8192;
  if (blockIdx.z == 0) {
    int w = t >> 6, l = t & 63;
    int l16 = l & 15, quad = l >> 4;
    #pragma unroll
    for (int fi = 0; fi < 4; ++fi) {
      int f = w * 4 + fi;
      int nt = f >> 2, kf = f & 3;
      const U16* src = qkv + ((size_t)(b * 2048 + kc * 64 + nt * 16 + l16)) * 3072 + 1024 + h * 128 + kf * 32 + quad * 8;
      *(uint4*)(Kp + dstB + (size_t)f * 512 + l * 8) = *(const uint4*)src;
    }
  } else {
    int r = t >> 2, c0 = (t & 3) * 32;
    const U16* src = qkv + ((size_t)(b * 2048 + kc * 64 + r)) * 3072 + 2048 + h * 128 + c0;
    #pragma unroll
    for (int q = 0; q < 8; ++q)
      *(ushort4*)&tile[r][c0 + q * 4] = *(const ushort4*)(src + q * 4);
    __syncthreads();
    #pragma unroll
    for (int i = 0; i < 4; ++i) {
      int p = t + 256 * i;
      int g = p >> 6, l = p & 63;
      int l16 = l & 15, quad = l >> 4;
      int nt = g >> 1, kf = g & 1;
      U16 vals[8];
      #pragma unroll
      for (int j = 0; j < 8; ++j) vals[j] = tile[kf * 32 + quad * 8 + j][nt * 16 + l16];
      *(uint4*)(Vp + dstB + (size_t)g * 512 + l * 8) = *(const uint4*)vals;
    }
  }
}

// ---------- zero z+G scratch (in d_out) ----------
__global__ __launch_bounds__(256) void zero_zg_kernel(float* __restrict__ zg) {
  int id = blockIdx.x * 256 + threadIdx.x;
  if (id < 294912) zg[id] = 0.f;
}

// ---------- MFMA fused attention: 32 q-rows/block, 32-row k-chunks, k-split x2 ----------
// Rationale (R3 post-mortem): kernel is L2-BW-bound on K/V streaming. 32 q-rows per
// block doubles arithmetic intensity -> per-CU K/V bytes halve. Regs budgeted <=256
// (afr 32 + bK 32 + bV 32 + oacc 64 + z/g 16 + temps) to keep 8 waves/CU.
// zg[0..32768): z per m*8+h (atomicAdd); zg[32768..294912): Gram per m*64+h1*8+h2.
// half0 O -> O32a f32; half1 O -> dead K/V stripes of qkv rows (f32).
#define EHST 1040          // per-head e-region stride (U16): 2 subs * 512 + pad
#define EBST (8 * EHST)    // per-buffer stride
__global__ __launch_bounds__(512, 2) void attn_mfma_kernel(U16* __restrict__ qkv,
                                                           const U16* __restrict__ Kp, const U16* __restrict__ Vp,
                                                           float* __restrict__ O32a,
                                                           float* __restrict__ zg) {
  __shared__ U16 ebuf[2 * EBST];
  int t = threadIdx.x;
  int w = t >> 6;          // head
  int l = t & 63;
  int l16 = l & 15, quad = l >> 4;
  int idx = blockIdx.x;
  int khalf = idx & 1;
  int b = (idx >> 1) & 1;
  int q0 = (idx >> 2) * 32;
  size_t rowB = (size_t)b * 2048;
  const float sc = 0.08838834764831845f;
  const int c0 = khalf * 32, cend = c0 + 32;   // 32-row chunks, 64 total over k=2048

  // Q A-frags for both q-subs: A[m=q=l16][d=kf*32+quad*8+j]
  bf16x8 afr[2][4];
  #pragma unroll
  for (int s = 0; s < 2; ++s) {
    const U16* Qb = qkv + (rowB + q0 + s * 16 + l16) * 3072 + w * 128 + quad * 8;
    #pragma unroll
    for (int kf = 0; kf < 4; ++kf) afr[s][kf] = *(const bf16x8*)(Qb + kf * 32);
  }

  f32x4 oacc[2][8];
  #pragma unroll
  for (int s = 0; s < 2; ++s)
    #pragma unroll
    for (int i = 0; i < 8; ++i) oacc[s][i] = (f32x4){0.f, 0.f, 0.f, 0.f};
  f32x4 gacc[2];
  gacc[0] = (f32x4){0.f, 0.f, 0.f, 0.f};
  gacc[1] = (f32x4){0.f, 0.f, 0.f, 0.f};
  float zacc[2][4] = {{0.f, 0.f, 0.f, 0.f}, {0.f, 0.f, 0.f, 0.f}};

  const U16* KpB = Kp + (size_t)(b * 8 + w) * 262144;   // 32 packed 64-chunks * 8192
  const U16* VpB = Vp + (size_t)(b * 8 + w) * 262144;

  // register-resident K and V for current 32-chunk
  // K sub-chunk c: packed chunk c>>1, nt rows {(c&1)*2, +1}, kf 0..3
  // V sub-chunk c: packed chunk c>>1, g = nt*2 + (c&1), nt(d-group) 0..7
  bf16x8 bK[2][4];   // 32 VGPR
  bf16x8 bV[8];      // 32 VGPR
  {
    int kc64 = c0 >> 1, nh = (c0 & 1) * 2, vk = c0 & 1;
    #pragma unroll
    for (int i = 0; i < 2; ++i)
      #pragma unroll
      for (int kf = 0; kf < 4; ++kf)
        bK[i][kf] = *(const bf16x8*)(KpB + (size_t)kc64 * 8192 + (size_t)((nh + i) * 4 + kf) * 512 + l * 8);
    #pragma unroll
    for (int nt = 0; nt < 8; ++nt)
      bV[nt] = *(const bf16x8*)(VpB + (size_t)kc64 * 8192 + (size_t)(nt * 2 + vk) * 512 + l * 8);
  }

  for (int c = c0; c < cend; ++c) {
    // QK^T (both subs)
    f32x4 sacc[2][2];
    #pragma unroll
    for (int s = 0; s < 2; ++s)
      #pragma unroll
      for (int i = 0; i < 2; ++i) {
        sacc[s][i] = (f32x4){0.f, 0.f, 0.f, 0.f};
        #pragma unroll
        for (int kf = 0; kf < 4; ++kf)
          sacc[s][i] = __builtin_amdgcn_mfma_f32_16x16x32_bf16(afr[s][kf], bK[i][kf], sacc[s][i], 0, 0, 0);
      }
    // exp + z-accum + e store (frag-major per wave region, per sub)
    U16* eb = &ebuf[(c & 1) * EBST + w * EHST];
    #pragma unroll
    for (int s = 0; s < 2; ++s) {
      #pragma unroll
      for (int i = 0; i < 2; ++i) {
        int kq = i * 2 + (l16 >> 3);
        int j = l16 & 7;
        #pragma unroll
        for (int r = 0; r < 4; ++r) {
          float e = __expf(fminf(sacc[s][i][r] * sc, 30.f));
          zacc[s][r] += e;
          eb[s * 512 + kq * 128 + (quad * 4 + r) * 8 + j] = f2bf(e);
        }
      }
    }
    __syncthreads();
    // prefetch next sub-chunk K AFTER barrier (bK consumed by QK above)
    if (c + 1 < cend) {
      int cn = c + 1, kc64 = cn >> 1, nh = (cn & 1) * 2;
      #pragma unroll
      for (int i = 0; i < 2; ++i)
        #pragma unroll
        for (int kf = 0; kf < 4; ++kf)
          bK[i][kf] = *(const bf16x8*)(KpB + (size_t)kc64 * 8192 + (size_t)((nh + i) * 4 + kf) * 512 + l * 8);
    }
    // PV: A = own-head e from LDS, B = register-resident bV
    #pragma unroll
    for (int s = 0; s < 2; ++s) {
      bf16x8 pfr = *(const bf16x8*)&eb[s * 512 + l * 8];
      #pragma unroll
      for (int nt = 0; nt < 8; ++nt)
        oacc[s][nt] = __builtin_amdgcn_mfma_f32_16x16x32_bf16(pfr, bV[nt], oacc[s][nt], 0, 0, 0);
    }
    // prefetch next sub-chunk V AFTER PV consumed bV
    if (c + 1 < cend) {
      int cn = c + 1, kc64 = cn >> 1, vk = cn & 1;
      #pragma unroll
      for (int nt = 0; nt < 8; ++nt)
        bV[nt] = *(const bf16x8*)(VpB + (size_t)kc64 * 8192 + (size_t)(nt * 2 + vk) * 512 + l * 8);
    }
    // Gram: A=B=e-frag with m=(h' + 8*q-parity), q-pair = w, per sub
    {
      const U16* gb = &ebuf[(c & 1) * EBST];
      #pragma unroll
      for (int s = 0; s < 2; ++s) {
        bf16x8 gfr = *(const bf16x8*)(gb + (size_t)(l & 7) * EHST + s * 512
                                      + (quad * 16 + w * 2 + ((l >> 3) & 1)) * 8);
        gacc[s] = __builtin_amdgcn_mfma_f32_16x16x32_bf16(gfr, gfr, gacc[s], 0, 0, 0);
      }
    }
  }
  // Z reduce (butterfly over 16 k-columns) + atomic into zg
  #pragma unroll
  for (int s = 0; s < 2; ++s)
    #pragma unroll
    for (int r = 0; r < 4; ++r) {
      float z = zacc[s][r];
      z += __shfl_xor(z, 1); z += __shfl_xor(z, 2);
      z += __shfl_xor(z, 4); z += __shfl_xor(z, 8);
      zacc[s][r] = z;
    }
  if (l16 == 0) {
    #pragma unroll
    for (int s = 0; s < 2; ++s)
      #pragma unroll
      for (int r = 0; r < 4; ++r) {
        size_t m = rowB + q0 + s * 16 + quad * 4 + r;
        atomicAdd(&zg[m * 8 + w], zacc[s][r]);
      }
  }
  // O partial store (unnormalized f32)
  #pragma unroll
  for (int s = 0; s < 2; ++s)
    #pragma unroll
    for (int r = 0; r < 4; ++r) {
      size_t m = rowB + q0 + s * 16 + quad * 4 + r;
      float* orow;
      if (khalf == 0) orow = O32a + m * 1024 + w * 128 + l16;
      else            orow = (float*)(qkv + m * 3072 + 1024) + w * 128 + l16;   // dead K/V stripe
      #pragma unroll
      for (int nt = 0; nt < 8; ++nt) orow[nt * 16] = oacc[s][nt][r];
    }
  // Gram partial: valid entries have m-parity == n-parity
  {
    int h2 = l16 & 7, b2 = l16 >> 3;
    int a = quad >> 1;
    if (a == b2) {
      float* G = zg + 32768;
      #pragma unroll
      for (int s = 0; s < 2; ++s) {
        size_t m = rowB + q0 + s * 16 + w * 2 + a;
        #pragma unroll
        for (int r = 0; r < 4; ++r) {
          int h1 = (quad * 4 + r) & 7;
          atomicAdd(&G[m * 64 + h1 * 8 + h2], gacc[s][r]);
        }
      }
    }
  }
}

// ---------- combine O halves + normalize by total z -> bf16 O16 ----------
__global__ __launch_bounds__(256) void attn_norm_kernel(const float* __restrict__ O32a, const U16* __restrict__ qkv,
                                                        const float* __restrict__ zg, U16* __restrict__ O16) {
  int id = blockIdx.x * 256 + threadIdx.x;   // 1048576 threads * 4 f32
  int base = id * 4;
  int m = base >> 10, d = base & 1023;
  const float* ob = (const float*)(qkv + (size_t)m * 3072 + 1024);
  float4 a = *(const float4*)&O32a[base];
  float4 bv = *(const float4*)&ob[d];
  float inv = 1.f / zg[m * 8 + (d >> 7)];
  ushort4 o;
  o.x = f2bf((a.x + bv.x) * inv);
  o.y = f2bf((a.y + bv.y) * inv);
  o.z = f2bf((a.z + bv.z) * inv);
  o.w = f2bf((a.w + bv.w) * inv);
  *(ushort4*)&O16[base] = o;
}

// ---------- gram finalize: sum G/(z1*z2)/64 - 2 into scal[slot] ----------
__global__ __launch_bounds__(256) void gram_fin_kernel(const float* __restrict__ zg, float* __restrict__ scal, int slot) {
  __shared__ float red[256];
  int t = threadIdx.x;
  const float* G = zg + 32768;
  float s = 0.f;
  for (int i = blockIdx.x * 256 * 16 + t; i < (blockIdx.x + 1) * 256 * 16; i += 256) {
    int m = i >> 6, h1 = (i >> 3) & 7, h2 = i & 7;
    s += G[i] / (zg[m * 8 + h1] * zg[m * 8 + h2]);
  }
  red[t] = s; __syncthreads();
  for (int o = 128; o; o >>= 1) { if (t < o) red[t] += red[t + o]; __syncthreads(); }
  if (t == 0) atomicAdd(&scal[slot], red[0] * (1.f / 64.f) - (blockIdx.x == 0 ? 2.0f : 0.0f));
}

// ---------- residual + LayerNorm (writes fp32 + bf16 mirror) ----------
__global__ __launch_bounds__(256) void ln_kernel(float* __restrict__ cellsB, U16* __restrict__ cellsB16,
                                                 const float* __restrict__ proj,
                                                 const void* __restrict__ gv, const void* __restrict__ bv, long off,
                                                 const float* __restrict__ scal) {
  __shared__ float red[256];
  bool bf = scal[16] != 0.f;
  int row = blockIdx.x, t = threadIdx.x;
  size_t base = (size_t)row * 1024;
  int d = 4 * t;
  float4 cv = *(const float4*)&cellsB[base + d];
  float4 pv = *(const float4*)&proj[base + d];
  float v0 = cv.x + pv.x, v1 = cv.y + pv.y, v2 = cv.z + pv.z, v3 = cv.w + pv.w;
  red[t] = v0 + v1 + v2 + v3; __syncthreads();
  for (int o = 128; o; o >>= 1) { if (t < o) red[t] += red[t + o]; __syncthreads(); }
  float mu = red[0] * (1.f / 1024.f);
  __syncthreads();
  float d0 = v0 - mu, d1 = v1 - mu, d2 = v2 - mu, d3 = v3 - mu;
  red[t] = d0 * d0 + d1 * d1 + d2 * d2 + d3 * d3; __syncthreads();
  for (int o = 128; o; o >>= 1) { if (t < o) red[t] += red[t + o]; __syncthreads(); }
  float rstd = rsqrtf(red[0] * (1.f / 1024.f) + 1e-5f);
  float4 out;
  out.x = d0 * rstd * ldv(gv, off + d, bf)     + ldv(bv, off + d, bf);
  out.y = d1 * rstd * ldv(gv, off + d + 1, bf) + ldv(bv, off + d + 1, bf);
  out.z = d2 * rstd * ldv(gv, off + d + 2, bf) + ldv(bv, off + d + 2, bf);
  out.w = d3 * rstd * ldv(gv, off + d + 3, bf) + ldv(bv, off + d + 3, bf);
  *(float4*)&cellsB[base + d] = out;
  ushort4 ob;
  ob.x = f2bf(out.x); ob.y = f2bf(out.y); ob.z = f2bf(out.z); ob.w = f2bf(out.w);
  *(ushort4*)&cellsB16[base + d] = ob;
}

// ---------- tension finalize ----------
__global__ void tension_kernel(const float* __restrict__ scal, void* __restrict__ out) {
  bool bf = scal[16] != 0.f;
  float cnt = 8388608.f;
  float ten = 0.f;
  for (int l = 0; l < 2; ++l) {
    float v = scal[8 + l] / (cnt - 1.f);
    ten += sqrtf(fmaxf(v, 0.f));
  }
  ten *= 0.5f;
  if (bf) ((U16*)out)[2097152] = f2bf(ten);
  else    ((float*)out)[2097152] = ten;
}

extern "C" void kernel_launch(void* const* d_in, const int* in_sizes, int n_in,
                              void* d_out, int out_size, void* d_ws, size_t ws_size,
                              hipStream_t stream) {
  const void* X    = d_in[0];
  const void* AR   = d_in[1];
  const void* AI   = d_in[2];
  const void* CRc  = d_in[3];
  const void* CIc  = d_in[4];
  const void* CE   = d_in[5];
  const void* FS   = d_in[6];
  const void* WIN  = d_in[7];
  const void* BIN  = d_in[8];
  const void* AIW  = d_in[9];
  const void* AIB  = d_in[10];
  const void* AOW  = d_in[11];
  const void* AOB  = d_in[12];
  const void* LNG  = d_in[13];
  const void* LNB  = d_in[14];
  const void* WOUT = d_in[15];
  const void* BOUT = d_in[16];
  const int* STEP  = (const int*)d_in[17];

  // ws layout (float offsets), total ~75.6 MB (unchanged)
  float* ws = (float*)d_ws;
  float* scal  = ws;                  // 64
  float* probs = ws + 64;
  float* ph    = ws + 64 + 2048;
  float* fmean = ws + 64 + 4096;
  float* xp    = ws + 64 + 12288;
  float* cells = ws + 16384;           // 2M f (dead after cellsB_kernel -> reused as Vp)
  float* CB    = ws + 16384 + 2097152; // 16.78M f region
  // phase 1:
  float* ar = CB;
  float* ai = CB + 4194304;
  float* cr = CB + 8388608;
  float* ci = CB + 12582912;
  // phase 2 (aliases phase 1):
  float* cellsB   = CB;                                   // [0 .. 4M)
  U16*   qkv16    = (U16*)(CB + 4194304);                 // [4M .. 10.49M) x U16; K/V stripes dead after pack -> O half1
  float* proj     = CB + 4194304;                         // aliases dead qkv
  float* O32a     = CB + 10485760;                        // [10.49 .. 14.68M) f32 partial O half0
  U16*   cellsB16 = (U16*)(CB + 12582912);                // rebuilt by ln each layer (dead during attn)
  U16*   Kp       = (U16*)(CB + 14680064);                // [14.68 .. 16.78M) = 4M U16; after attn reused as O16
  U16*   Vp       = (U16*)cells;                          // cells region dead in phase 2: 4M U16
  U16*   O16      = Kp;                                   // bf16 normalized O (Kp dead post-attn)
  float* zg       = (float*)d_out;                        // scratch: z[32768] + G[262144] (overwritten by final gemm)

  init_kernel<<<1, 256, 0, stream>>>(X, (const U16*)LNG, scal);

  for (int w = 0; w < 2; ++w) {
    if (w == 0) walk_coined_kernel<<<8192, 256, 0, stream>>>(AR, AI, cr, ci, CRc, CIc, scal, 0);
    else        walk_coined_kernel<<<8192, 256, 0, stream>>>(ar, ai, cr, ci, CRc, CIc, scal, 1);
    walk_new_stats_kernel<<<2048, 256, 0, stream>>>(cr, ci, ar, ai, scal, scal, 1 + w, probs, ph);
    inject_cells_kernel<<<4096, 256, 0, stream>>>(w == 0 ? CE : (const void*)cells, cells,
                                                  probs, ph, scal, 1 + w, w == 0 ? 1 : 0);
  }
  frustration_kernel<<<1024, 64, 0, stream>>>(cells, FS, scal);
  standing_kernel<<<8192, 256, 0, stream>>>(cells, STEP);
  morphism_kernel<<<1024, 64, 0, stream>>>(cells, STEP);
  faction_mean_kernel<<<32, 256, 0, stream>>>(cells, fmean);
  faction_apply_kernel<<<8192, 256, 0, stream>>>(cells, fmean, STEP);

  xproj_kernel<<<8, 256, 0, stream>>>(X, WIN, BIN, xp, scal);
  cellsB_kernel<<<16384, 256, 0, stream>>>(cells, xp, cellsB, cellsB16);
  // cells region now dead -> Vp

  for (int l = 0; l < 2; ++l) {
    mfma_gemm_kernel<<<dim3(24, 32), 256, 0, stream>>>(cellsB16, 0, AIW, (long)l * 3072 * 1024,
                                                       AIB, (long)l * 3072, qkv16, 3072, 1, scal);
    pack_kv_kernel<<<dim3(32, 16, 2), 256, 0, stream>>>(qkv16, Kp, Vp);
    zero_zg_kernel<<<1152, 256, 0, stream>>>(zg);
    attn_mfma_kernel<<<256, 512, 0, stream>>>(qkv16, Kp, Vp, O32a, zg);
    attn_norm_kernel<<<4096, 256, 0, stream>>>(O32a, qkv16, zg, O16);
    gram_fin_kernel<<<64, 256, 0, stream>>>(zg, scal, 8 + l);
    mfma_gemm_kernel<<<dim3(8, 32), 256, 0, stream>>>(O16, 0, AOW, (long)l * 1024 * 1024,
                                                      AOB, (long)l * 1024, proj, 1024, 0, scal);
    ln_kernel<<<4096, 256, 0, stream>>>(cellsB, cellsB16, proj, LNG, LNB, (long)l * 1024, scal);
  }
  mfma_gemm_kernel<<<dim3(4, 32), 256, 0, stream>>>(cellsB16, 0, WOUT, 0, BOUT, 0, d_out, 512, 2, scal);
  tension_kernel<<<1, 1, 0, stream>>>(scal, d_out);
}

// Round 5
// 785.810 us; speedup vs baseline: 1.2696x; 1.1652x over previous
//
#include <hip/hip_runtime.h>

#define U16 unsigned short

typedef short bf16x8 __attribute__((ext_vector_type(8)));
typedef float f32x4 __attribute__((ext_vector_type(4)));

// ---------- bf16 helpers ----------
__device__ __forceinline__ float bfp(const U16* p) { return __uint_as_float(((unsigned)(*p)) << 16); }
__device__ __forceinline__ U16 f2bf(float f) {
  unsigned u = __float_as_uint(f);
  u += 0x7FFFu + ((u >> 16) & 1u);
  return (U16)(u >> 16);
}
__device__ __forceinline__ float ldv(const void* p, long i, bool bf) {
  return bf ? bfp((const U16*)p + i) : ((const float*)p)[i];
}
// async global->LDS, 16B per lane; LDS dest is wave-uniform base (+lane*16 by HW),
// global src is per-lane (pre-swizzled to match fragment-major layout).
__device__ __forceinline__ void gload_lds16(const U16* g, U16* l) {
  __builtin_amdgcn_global_load_lds((const __attribute__((address_space(1))) void*)g,
                                   (__attribute__((address_space(3))) void*)l, 16, 0, 0);
}

// scal slots: 0=x_mean, 1..2=walk norms (S_raw, == raw prob sums), 8..9=tension Sq, 16=bf16 flag

// ---------- init: dtype detect + x_mean + zero scalar slab ----------
__global__ __launch_bounds__(256) void init_kernel(const void* __restrict__ x, const U16* __restrict__ lng,
                                                   float* __restrict__ scal) {
  __shared__ float red[256];
  __shared__ int fl;
  int t = threadIdx.x;
  if (t == 0) fl = (lng[0] != 0) ? 1 : 0;   // ln_g==1.0: bf16 -> 0x3F80, fp32 low half -> 0x0000
  __syncthreads();
  bool bf = fl != 0;
  float s = 0.f;
  for (int i = t; i < 1024; i += 256) s += ldv(x, i, bf);
  red[t] = s; __syncthreads();
  for (int o = 128; o; o >>= 1) { if (t < o) red[t] += red[t + o]; __syncthreads(); }
  if (t == 0) { scal[0] = red[0] * (1.f / 1024.f); scal[16] = bf ? 1.f : 0.f; }
  else if (t < 64 && t != 16) scal[t] = 0.f;
}

// ---------- quantum walk: coined ----------
__global__ __launch_bounds__(256) void walk_coined_kernel(const void* __restrict__ arv, const void* __restrict__ aiv,
                                                          float* __restrict__ cr, float* __restrict__ ci,
                                                          const void* __restrict__ coinR, const void* __restrict__ coinI,
                                                          const float* __restrict__ scal, int iter) {
  bool bf = scal[16] != 0.f;
  int id = blockIdx.x * 256 + threadIdx.x;   // (n,d): 2048*1024
  int n = id >> 10, d = id & 1023;
  size_t b0 = (size_t)n * 2048 + d;
  float pre = 1.f;
  float a0r, a0i, a1r, a1i;
  if (iter == 0) {
    a0r = ldv(arv, b0, bf); a1r = ldv(arv, b0 + 1024, bf);
    a0i = ldv(aiv, b0, bf); a1i = ldv(aiv, b0 + 1024, bf);
  } else {
    pre = 1.f / (sqrtf(scal[iter]) + 1e-8f);
    const float* ar = (const float*)arv;
    const float* ai = (const float*)aiv;
    a0r = ar[b0]; a1r = ar[b0 + 1024]; a0i = ai[b0]; a1i = ai[b0 + 1024];
  }
  a0r *= pre; a0i *= pre; a1r *= pre; a1i *= pre;
  float c00r = ldv(coinR, 0, bf), c01r = ldv(coinR, 1, bf), c10r = ldv(coinR, 2, bf), c11r = ldv(coinR, 3, bf);
  float c00i = ldv(coinI, 0, bf), c01i = ldv(coinI, 1, bf), c10i = ldv(coinI, 2, bf), c11i = ldv(coinI, 3, bf);
  cr[b0]        = c00r * a0r - c00i * a0i + c01r * a1r - c01i * a1i;
  ci[b0]        = c00r * a0i + c00i * a0r + c01r * a1i + c01i * a1r;
  cr[b0 + 1024] = c10r * a0r - c10i * a0i + c11r * a1r - c11i * a1i;
  ci[b0 + 1024] = c10r * a0i + c10i * a0r + c11r * a1i + c11i * a1r;
}

// ---------- fused walk_new + inject_stats ----------
__global__ __launch_bounds__(256) void walk_new_stats_kernel(const float* __restrict__ cr, const float* __restrict__ ci,
                                                             float* __restrict__ ar, float* __restrict__ ai,
                                                             const float* __restrict__ scal, float* __restrict__ scalw,
                                                             int slot, float* __restrict__ probs, float* __restrict__ ph) {
  __shared__ float r1[256], r2[256];
  int n = blockIdx.x, t = threadIdx.x;
  float th = scal[0] * 0.1f;
  float sn, cs; sincosf(th, &sn, &cs);
  float pacc = 0.f, phacc = 0.f;
  #pragma unroll
  for (int it = 0; it < 4; ++it) {
    int d = t + it * 256;
    size_t b0 = (size_t)n * 2048 + d;
    float n0r = cr[b0], n0i = ci[b0];
    float s1r = 0.f, s1i = 0.f;
    #pragma unroll
    for (int k = 0; k < 11; ++k) {
      size_t j = (size_t)(n ^ (1 << k)) * 2048 + 1024 + d;
      s1r += cr[j]; s1i += ci[j];
    }
    s1r *= (1.f / 11.f); s1i *= (1.f / 11.f);
    float o0r = n0r * cs - n0i * sn, o0i = n0r * sn + n0i * cs;
    float o1r = s1r * cs - s1i * sn, o1i = s1r * sn + s1i * cs;
    ar[b0] = o0r; ai[b0] = o0i; ar[b0 + 1024] = o1r; ai[b0 + 1024] = o1i;
    pacc += o0r * o0r + o0i * o0i + o1r * o1r + o1i * o1i;
    phacc += atan2f(o0i + o1i, o0r + o1r);
  }
  r1[t] = pacc; r2[t] = phacc; __syncthreads();
  for (int o = 128; o; o >>= 1) { if (t < o) { r1[t] += r1[t + o]; r2[t] += r2[t + o]; } __syncthreads(); }
  if (t == 0) { probs[n] = r1[0]; ph[n] = r2[0] * (1.f / 1024.f); atomicAdd(&scalw[slot], r1[0]); }
}

// ---------- inject ----------
__global__ __launch_bounds__(256) void inject_cells_kernel(const void* __restrict__ cellsIn, float* __restrict__ cells,
                                                           const float* __restrict__ probs,
                                                           const float* __restrict__ ph, const float* __restrict__ scal,
                                                           int wslot, int useRaw) {
  bool bf = scal[16] != 0.f;
  int id = blockIdx.x * 256 + threadIdx.x;   // 2048*512
  int c = id >> 9, d = id & 511;
  float invn = 1.f / (sqrtf(scal[wslot]) + 1e-8f);
  float inv2 = invn * invn;
  float denom = 1.f / (scal[wslot] * inv2 + 1e-8f);
  float psc = inv2 * denom;
  float p = probs[c] * psc;
  float interf = 0.f;
  #pragma unroll
  for (int j = 0; j < 6; ++j) interf += (p - probs[c ^ (1 << j)] * psc);
  interf *= 0.03f;
  float scale = 0.8f + 0.4f * p;
  float phc = ph[c] * 0.3f;
  float sn, cs; sincosf(phc, &sn, &cs);
  size_t base = (size_t)c * 1024 + d;
  float h1, h2;
  if (useRaw) { h1 = ldv(cellsIn, base, bf) * scale; h2 = ldv(cellsIn, base + 512, bf) * scale; }
  else        { h1 = cells[base] * scale;            h2 = cells[base + 512] * scale; }
  float r1 = h1 * cs - h2 * sn, r2 = h1 * sn + h2 * cs;
  cells[base]       = 0.5f * (r1 + h1) + interf;
  cells[base + 512] = 0.5f * (r2 + h2) + interf;
}

// ---------- frustration: one wave per column, rows in registers, shuffle chain ----------
__global__ __launch_bounds__(64) void frustration_kernel(float* __restrict__ cells, const void* __restrict__ fs,
                                                         const float* __restrict__ scal) {
  bool bf = scal[16] != 0.f;
  int d = blockIdx.x;      // 1024 columns
  int l = threadIdx.x;     // 64 lanes
  float s0 = ldv(fs, l, bf);
  float s1 = ldv(fs, l + 64, bf);
  float w0 = s0 * cells[(size_t)l * 1024 + d];
  float w1 = s1 * cells[(size_t)(l + 64) * 1024 + d];
  float stat0 = 0.f, stat1 = 0.f;
  #pragma unroll
  for (int b = 7; b < 10; ++b) {
    int j0 = l ^ (1 << b);
    int j1 = (l + 64) ^ (1 << b);
    stat0 += ldv(fs, j0, bf) * cells[(size_t)j0 * 1024 + d];
    stat1 += ldv(fs, j1, bf) * cells[(size_t)j1 * 1024 + d];
  }
  #pragma unroll
  for (int i = 0; i < 128; ++i) {
    const int hi = i >> 6;
    const int li = i & 63;
    float vsrc = (hi == 0) ? w0 : w1;
    float voth = (hi == 0) ? w1 : w0;
    float acc = __shfl(vsrc, li ^ 1) + __shfl(vsrc, li ^ 2) + __shfl(vsrc, li ^ 4)
              + __shfl(vsrc, li ^ 8) + __shfl(vsrc, li ^ 16) + __shfl(vsrc, li ^ 32)
              + __shfl(voth, li);
    if (l == li) {
      if (hi == 0) w0 = 0.85f * w0 + 0.015f * (acc + stat0);
      else         w1 = 0.85f * w1 + 0.015f * (acc + stat1);
    }
  }
  cells[(size_t)l * 1024 + d]        = s0 * w0;
  cells[(size_t)(l + 64) * 1024 + d] = s1 * w1;
}

// ---------- standing wave ----------
__global__ __launch_bounds__(256) void standing_kernel(float* __restrict__ cells, const int* __restrict__ stepp) {
  int id = blockIdx.x * 256 + threadIdx.x;   // 2M
  int c = id >> 10;
  float st = (float)stepp[0] * 0.15f;
  float fwd = fmodf(st, 2048.f);
  float bwd = fmodf(2048.f - st, 2048.f);
  float fi = (float)c;
  float r1 = 1.f / coshf((fi - fwd) * 0.5f);
  float r2 = 1.f / coshf((fi - bwd) * 0.5f);
  cells[id] *= (1.f + 0.03f * (r1 * r1 + r2 * r2));
}

// ---------- morphism: one wave per column, rows in registers, shuffle reduce ----------
__global__ __launch_bounds__(64) void morphism_kernel(float* __restrict__ cells, const int* __restrict__ stepp) {
  if (stepp[0] % 3 != 0) return;
  int d = blockIdx.x;        // 1024 columns
  int l = threadIdx.x;       // 64 lanes, 0..47 active
  float v = 0.f;
  if (l < 48) v = cells[(size_t)l * 1024 + d];
  for (int i = 0; i < 48; ++i) {
    float vi = __shfl(v, i);
    float x = v - vi;
    float e2 = __expf(2.f * x);
    float th = (l < 48) ? (1.f - 2.f / (e2 + 1.f)) : 0.f;
    th += __shfl_xor(th, 1);
    th += __shfl_xor(th, 2);
    th += __shfl_xor(th, 4);
    th += __shfl_xor(th, 8);
    th += __shfl_xor(th, 16);
    th += __shfl_xor(th, 32);
    if (l == i) v = 0.9f * v + (0.1f / 47.f) * th;
  }
  if (l < 48) cells[(size_t)l * 1024 + d] = v;
}

// ---------- faction ----------
__global__ __launch_bounds__(256) void faction_mean_kernel(const float* __restrict__ cells, float* __restrict__ fmean) {
  int id = blockIdx.x * 256 + threadIdx.x;   // 8*1024
  int f = id >> 10, d = id & 1023;
  float s = 0.f;
  for (int r = 0; r < 256; ++r) s += cells[(size_t)((f << 8) + r) * 1024 + d];
  fmean[id] = s * (1.f / 256.f);
}
__global__ __launch_bounds__(256) void faction_apply_kernel(float* __restrict__ cells, const float* __restrict__ fmean,
                                                            const int* __restrict__ stepp) {
  int id = blockIdx.x * 256 + threadIdx.x;   // 2M
  int c = id >> 10, d = id & 1023;
  int f = c >> 8, r = c & 255;
  float v = 0.85f * cells[id] + 0.15f * fmean[f * 1024 + d];
  if (stepp[0] > 5 && r < 64) {
    float g = 0.f;
    #pragma unroll
    for (int ff = 0; ff < 8; ++ff) g += fmean[ff * 1024 + d];
    v = 0.85f * v + 0.15f * g * 0.125f;
  }
  cells[id] = v;
}

// ---------- x projection ----------
__global__ __launch_bounds__(256) void xproj_kernel(const void* __restrict__ x, const void* __restrict__ w_in,
                                                    const void* __restrict__ b_in, float* __restrict__ xp,
                                                    const float* __restrict__ scal) {
  bool bf = scal[16] != 0.f;
  int id = blockIdx.x * 256 + threadIdx.x;   // 2048
  int b = id >> 10, o = id & 1023;
  float acc = ldv(b_in, o, bf);
  if (bf) {
    const U16* xr = (const U16*)x + b * 512;
    const U16* wr = (const U16*)w_in + (long)o * 512;
    for (int k = 0; k < 512; ++k) acc += bfp(xr + k) * bfp(wr + k);
  } else {
    const float* xr = (const float*)x + b * 512;
    const float* wr = (const float*)w_in + (long)o * 512;
    for (int k = 0; k < 512; ++k) acc += xr[k] * wr[k];
  }
  xp[id] = acc;
}

// writes fp32 cellsB + bf16 mirror
__global__ __launch_bounds__(256) void cellsB_kernel(const float* __restrict__ cells, const float* __restrict__ xp,
                                                     float* __restrict__ cellsB, U16* __restrict__ cellsB16) {
  int id = blockIdx.x * 256 + threadIdx.x;   // 4M
  int b = id >> 21;
  int cd = id & ((1 << 21) - 1);
  int d = id & 1023;
  float v = cells[cd] + 0.1f * xp[(b << 10) + d];
  cellsB[id] = v;
  cellsB16[id] = f2bf(v);
}

// ---------- weight pre-convert f32 -> bf16 (no-op when inputs already bf16) ----------
__global__ __launch_bounds__(256) void wcvt_kernel(const void* __restrict__ W, long off,
                                                   U16* __restrict__ dst, int n4,
                                                   const float* __restrict__ scal) {
  if (scal[16] != 0.f) return;   // bf16 inputs: gemm reads original weights directly
  int id = blockIdx.x * 256 + threadIdx.x;
  if (id < n4) {
    const float* src = (const float*)W + off;
    float4 v = *(const float4*)&src[(size_t)id * 4];
    ushort4 o;
    o.x = f2bf(v.x); o.y = f2bf(v.y); o.z = f2bf(v.z); o.w = f2bf(v.w);
    *(ushort4*)&dst[(size_t)id * 4] = o;
  }
}

// ---------- MFMA GEMM: C[M,N] = A[M,1024](bf16) * W[N,1024]^T + bias ----------
// Pure-bf16 both operands; staging via global_load_lds (async, 16B/lane) with
// pre-swizzled per-lane global source -> fragment-major LDS, linear dest (m97 structure).
// W source: original (if bf16 inputs) else pre-converted W16s scratch.
__global__ __launch_bounds__(256) void mfma_gemm_kernel(const U16* __restrict__ A16,
                                                        const void* __restrict__ Wv, long Woff,
                                                        const U16* __restrict__ W16s,
                                                        const void* __restrict__ biasv, long Boff,
                                                        void* __restrict__ Cout, int N, int mode,
                                                        const float* __restrict__ scal) {
  __shared__ U16 Al[4096];
  __shared__ U16 Wl[4096];
  bool bf = scal[16] != 0.f;
  const int K = 1024;
  int t = threadIdx.x;
  int wv = t >> 6, l = t & 63;
  int n0 = blockIdx.x * 128, m0 = blockIdx.y * 128;
  int wmt = (wv & 1) * 4;
  int wnt = (wv >> 1) * 4;
  const U16* Wb = bf ? (const U16*)Wv + Woff : W16s;

  // per-lane global sources for this wave's two A-fragments and two W-fragments.
  // fragment f content: lane l <- row (base + f*16 + (l&15)), k-slice (l>>4)*8
  int fr0 = wv * 2, fr1 = fr0 + 1;
  const U16* asrc0 = A16 + (size_t)(m0 + fr0 * 16 + (l & 15)) * K + (l >> 4) * 8;
  const U16* asrc1 = A16 + (size_t)(m0 + fr1 * 16 + (l & 15)) * K + (l >> 4) * 8;
  const U16* wsrc0 = Wb  + (size_t)(n0 + fr0 * 16 + (l & 15)) * K + (l >> 4) * 8;
  const U16* wsrc1 = Wb  + (size_t)(n0 + fr1 * 16 + (l & 15)) * K + (l >> 4) * 8;
  U16* adst0 = &Al[fr0 * 512];   // wave-uniform LDS base; HW adds lane*16B
  U16* adst1 = &Al[fr1 * 512];
  U16* wdst0 = &Wl[fr0 * 512];
  U16* wdst1 = &Wl[fr1 * 512];

  f32x4 acc[4][4];
  #pragma unroll
  for (int i = 0; i < 4; ++i)
    #pragma unroll
    for (int j = 0; j < 4; ++j) acc[i][j] = (f32x4){0.f, 0.f, 0.f, 0.f};

  for (int k0 = 0; k0 < K; k0 += 32) {
    __syncthreads();               // prev MFMA reads done -> LDS reusable
    gload_lds16(asrc0 + k0, adst0);
    gload_lds16(asrc1 + k0, adst1);
    gload_lds16(wsrc0 + k0, wdst0);
    gload_lds16(wsrc1 + k0, wdst1);
    __syncthreads();               // vmcnt(0) drain: tiles resident
    bf16x8 afr[4], bfr[4];
    #pragma unroll
    for (int i = 0; i < 4; ++i) afr[i] = *(const bf16x8*)&Al[((wmt + i) * 64 + l) * 8];
    #pragma unroll
    for (int j = 0; j < 4; ++j) bfr[j] = *(const bf16x8*)&Wl[((wnt + j) * 64 + l) * 8];
    #pragma unroll
    for (int i = 0; i < 4; ++i)
      #pragma unroll
      for (int j = 0; j < 4; ++j)
        acc[i][j] = __builtin_amdgcn_mfma_f32_16x16x32_bf16(afr[i], bfr[j], acc[i][j], 0, 0, 0);
  }
  bool outBf = (mode == 1) || (mode == 2 && bf);
  int cl = l & 15, rq = l >> 4;
  #pragma unroll
  for (int j = 0; j < 4; ++j) {
    int n = n0 + (wnt + j) * 16 + cl;
    float bv = ldv(biasv, Boff + n, bf);
    #pragma unroll
    for (int i = 0; i < 4; ++i) {
      int mrow = m0 + (wmt + i) * 16 + rq * 4;
      #pragma unroll
      for (int r = 0; r < 4; ++r) {
        float v = acc[i][j][r] + bv;
        if (outBf) ((U16*)Cout)[(size_t)(mrow + r) * N + n] = f2bf(v);
        else       ((float*)Cout)[(size_t)(mrow + r) * N + n] = v;
      }
    }
  }
}

// ---------- fused pack of K and V into fragment-major streams ----------
__global__ __launch_bounds__(256) void pack_kv_kernel(const U16* __restrict__ qkv,
                                                      U16* __restrict__ Kp, U16* __restrict__ Vp) {
  __shared__ U16 tile[64][132];
  int t = threadIdx.x;
  int kc = blockIdx.x, bh = blockIdx.y;
  int b = bh >> 3, h = bh & 7;
  size_t dstB = ((size_t)bh * 32 + kc) * 8192;
  if (blockIdx.z == 0) {
    int w = t >> 6, l = t & 63;
    int l16 = l & 15, quad = l >> 4;
    #pragma unroll
    for (int fi = 0; fi < 4; ++fi) {
      int f = w * 4 + fi;
      int nt = f >> 2, kf = f & 3;
      const U16* src = qkv + ((size_t)(b * 2048 + kc * 64 + nt * 16 + l16)) * 3072 + 1024 + h * 128 + kf * 32 + quad * 8;
      *(uint4*)(Kp + dstB + (size_t)f * 512 + l * 8) = *(const uint4*)src;
    }
  } else {
    int r = t >> 2, c0 = (t & 3) * 32;
    const U16* src = qkv + ((size_t)(b * 2048 + kc * 64 + r)) * 3072 + 2048 + h * 128 + c0;
    #pragma unroll
    for (int q = 0; q < 8; ++q)
      *(ushort4*)&tile[r][c0 + q * 4] = *(const ushort4*)(src + q * 4);
    __syncthreads();
    #pragma unroll
    for (int i = 0; i < 4; ++i) {
      int p = t + 256 * i;
      int g = p >> 6, l = p & 63;
      int l16 = l & 15, quad = l >> 4;
      int nt = g >> 1, kf = g & 1;
      U16 vals[8];
      #pragma unroll
      for (int j = 0; j < 8; ++j) vals[j] = tile[kf * 32 + quad * 8 + j][nt * 16 + l16];
      *(uint4*)(Vp + dstB + (size_t)g * 512 + l * 8) = *(const uint4*)vals;
    }
  }
}

// ---------- zero z+G scratch (in d_out) ----------
__global__ __launch_bounds__(256) void zero_zg_kernel(float* __restrict__ zg) {
  int id = blockIdx.x * 256 + threadIdx.x;
  if (id < 294912) zg[id] = 0.f;
}

// ---------- MFMA fused attention: 32 q-rows/block, 32-row k-chunks, k-split x2 ----------
#define EHST 1040          // per-head e-region stride (U16): 2 subs * 512 + pad
#define EBST (8 * EHST)    // per-buffer stride
__global__ __launch_bounds__(512, 2) void attn_mfma_kernel(U16* __restrict__ qkv,
                                                           const U16* __restrict__ Kp, const U16* __restrict__ Vp,
                                                           float* __restrict__ O32a,
                                                           float* __restrict__ zg) {
  __shared__ U16 ebuf[2 * EBST];
  int t = threadIdx.x;
  int w = t >> 6;          // head
  int l = t & 63;
  int l16 = l & 15, quad = l >> 4;
  int idx = blockIdx.x;
  int khalf = idx & 1;
  int b = (idx >> 1) & 1;
  int q0 = (idx >> 2) * 32;
  size_t rowB = (size_t)b * 2048;
  const float sc = 0.08838834764831845f;
  const int c0 = khalf * 32, cend = c0 + 32;   // 32-row chunks, 64 total over k=2048

  bf16x8 afr[2][4];
  #pragma unroll
  for (int s = 0; s < 2; ++s) {
    const U16* Qb = qkv + (rowB + q0 + s * 16 + l16) * 3072 + w * 128 + quad * 8;
    #pragma unroll
    for (int kf = 0; kf < 4; ++kf) afr[s][kf] = *(const bf16x8*)(Qb + kf * 32);
  }

  f32x4 oacc[2][8];
  #pragma unroll
  for (int s = 0; s < 2; ++s)
    #pragma unroll
    for (int i = 0; i < 8; ++i) oacc[s][i] = (f32x4){0.f, 0.f, 0.f, 0.f};
  f32x4 gacc[2];
  gacc[0] = (f32x4){0.f, 0.f, 0.f, 0.f};
  gacc[1] = (f32x4){0.f, 0.f, 0.f, 0.f};
  float zacc[2][4] = {{0.f, 0.f, 0.f, 0.f}, {0.f, 0.f, 0.f, 0.f}};

  const U16* KpB = Kp + (size_t)(b * 8 + w) * 262144;   // 32 packed 64-chunks * 8192
  const U16* VpB = Vp + (size_t)(b * 8 + w) * 262144;

  bf16x8 bK[2][4];   // 32 VGPR
  bf16x8 bV[8];      // 32 VGPR
  {
    int kc64 = c0 >> 1, nh = (c0 & 1) * 2, vk = c0 & 1;
    #pragma unroll
    for (int i = 0; i < 2; ++i)
      #pragma unroll
      for (int kf = 0; kf < 4; ++kf)
        bK[i][kf] = *(const bf16x8*)(KpB + (size_t)kc64 * 8192 + (size_t)((nh + i) * 4 + kf) * 512 + l * 8);
    #pragma unroll
    for (int nt = 0; nt < 8; ++nt)
      bV[nt] = *(const bf16x8*)(VpB + (size_t)kc64 * 8192 + (size_t)(nt * 2 + vk) * 512 + l * 8);
  }

  for (int c = c0; c < cend; ++c) {
    f32x4 sacc[2][2];
    #pragma unroll
    for (int s = 0; s < 2; ++s)
      #pragma unroll
      for (int i = 0; i < 2; ++i) {
        sacc[s][i] = (f32x4){0.f, 0.f, 0.f, 0.f};
        #pragma unroll
        for (int kf = 0; kf < 4; ++kf)
          sacc[s][i] = __builtin_amdgcn_mfma_f32_16x16x32_bf16(afr[s][kf], bK[i][kf], sacc[s][i], 0, 0, 0);
      }
    U16* eb = &ebuf[(c & 1) * EBST + w * EHST];
    #pragma unroll
    for (int s = 0; s < 2; ++s) {
      #pragma unroll
      for (int i = 0; i < 2; ++i) {
        int kq = i * 2 + (l16 >> 3);
        int j = l16 & 7;
        #pragma unroll
        for (int r = 0; r < 4; ++r) {
          float e = __expf(fminf(sacc[s][i][r] * sc, 30.f));
          zacc[s][r] += e;
          eb[s * 512 + kq * 128 + (quad * 4 + r) * 8 + j] = f2bf(e);
        }
      }
    }
    __syncthreads();
    if (c + 1 < cend) {
      int cn = c + 1, kc64 = cn >> 1, nh = (cn & 1) * 2;
      #pragma unroll
      for (int i = 0; i < 2; ++i)
        #pragma unroll
        for (int kf = 0; kf < 4; ++kf)
          bK[i][kf] = *(const bf16x8*)(KpB + (size_t)kc64 * 8192 + (size_t)((nh + i) * 4 + kf) * 512 + l * 8);
    }
    #pragma unroll
    for (int s = 0; s < 2; ++s) {
      bf16x8 pfr = *(const bf16x8*)&eb[s * 512 + l * 8];
      #pragma unroll
      for (int nt = 0; nt < 8; ++nt)
        oacc[s][nt] = __builtin_amdgcn_mfma_f32_16x16x32_bf16(pfr, bV[nt], oacc[s][nt], 0, 0, 0);
    }
    if (c + 1 < cend) {
      int cn = c + 1, kc64 = cn >> 1, vk = cn & 1;
      #pragma unroll
      for (int nt = 0; nt < 8; ++nt)
        bV[nt] = *(const bf16x8*)(VpB + (size_t)kc64 * 8192 + (size_t)(nt * 2 + vk) * 512 + l * 8);
    }
    {
      const U16* gb = &ebuf[(c & 1) * EBST];
      #pragma unroll
      for (int s = 0; s < 2; ++s) {
        bf16x8 gfr = *(const bf16x8*)(gb + (size_t)(l & 7) * EHST + s * 512
                                      + (quad * 16 + w * 2 + ((l >> 3) & 1)) * 8);
        gacc[s] = __builtin_amdgcn_mfma_f32_16x16x32_bf16(gfr, gfr, gacc[s], 0, 0, 0);
      }
    }
  }
  #pragma unroll
  for (int s = 0; s < 2; ++s)
    #pragma unroll
    for (int r = 0; r < 4; ++r) {
      float z = zacc[s][r];
      z += __shfl_xor(z, 1); z += __shfl_xor(z, 2);
      z += __shfl_xor(z, 4); z += __shfl_xor(z, 8);
      zacc[s][r] = z;
    }
  if (l16 == 0) {
    #pragma unroll
    for (int s = 0; s < 2; ++s)
      #pragma unroll
      for (int r = 0; r < 4; ++r) {
        size_t m = rowB + q0 + s * 16 + quad * 4 + r;
        atomicAdd(&zg[m * 8 + w], zacc[s][r]);
      }
  }
  #pragma unroll
  for (int s = 0; s < 2; ++s)
    #pragma unroll
    for (int r = 0; r < 4; ++r) {
      size_t m = rowB + q0 + s * 16 + quad * 4 + r;
      float* orow;
      if (khalf == 0) orow = O32a + m * 1024 + w * 128 + l16;
      else            orow = (float*)(qkv + m * 3072 + 1024) + w * 128 + l16;   // dead K/V stripe
      #pragma unroll
      for (int nt = 0; nt < 8; ++nt) orow[nt * 16] = oacc[s][nt][r];
    }
  {
    int h2 = l16 & 7, b2 = l16 >> 3;
    int a = quad >> 1;
    if (a == b2) {
      float* G = zg + 32768;
      #pragma unroll
      for (int s = 0; s < 2; ++s) {
        size_t m = rowB + q0 + s * 16 + w * 2 + a;
        #pragma unroll
        for (int r = 0; r < 4; ++r) {
          int h1 = (quad * 4 + r) & 7;
          atomicAdd(&G[m * 64 + h1 * 8 + h2], gacc[s][r]);
        }
      }
    }
  }
}

// ---------- combine O halves + normalize by total z -> bf16 O16 ----------
__global__ __launch_bounds__(256) void attn_norm_kernel(const float* __restrict__ O32a, const U16* __restrict__ qkv,
                                                        const float* __restrict__ zg, U16* __restrict__ O16) {
  int id = blockIdx.x * 256 + threadIdx.x;   // 1048576 threads * 4 f32
  int base = id * 4;
  int m = base >> 10, d = base & 1023;
  const float* ob = (const float*)(qkv + (size_t)m * 3072 + 1024);
  float4 a = *(const float4*)&O32a[base];
  float4 bv = *(const float4*)&ob[d];
  float inv = 1.f / zg[m * 8 + (d >> 7)];
  ushort4 o;
  o.x = f2bf((a.x + bv.x) * inv);
  o.y = f2bf((a.y + bv.y) * inv);
  o.z = f2bf((a.z + bv.z) * inv);
  o.w = f2bf((a.w + bv.w) * inv);
  *(ushort4*)&O16[base] = o;
}

// ---------- gram finalize: sum G/(z1*z2)/64 - 2 into scal[slot] ----------
__global__ __launch_bounds__(256) void gram_fin_kernel(const float* __restrict__ zg, float* __restrict__ scal, int slot) {
  __shared__ float red[256];
  int t = threadIdx.x;
  const float* G = zg + 32768;
  float s = 0.f;
  for (int i = blockIdx.x * 256 * 16 + t; i < (blockIdx.x + 1) * 256 * 16; i += 256) {
    int m = i >> 6, h1 = (i >> 3) & 7, h2 = i & 7;
    s += G[i] / (zg[m * 8 + h1] * zg[m * 8 + h2]);
  }
  red[t] = s; __syncthreads();
  for (int o = 128; o; o >>= 1) { if (t < o) red[t] += red[t + o]; __syncthreads(); }
  if (t == 0) atomicAdd(&scal[slot], red[0] * (1.f / 64.f) - (blockIdx.x == 0 ? 2.0f : 0.0f));
}

// ---------- residual + LayerNorm (writes fp32 + bf16 mirror) ----------
__global__ __launch_bounds__(256) void ln_kernel(float* __restrict__ cellsB, U16* __restrict__ cellsB16,
                                                 const float* __restrict__ proj,
                                                 const void* __restrict__ gv, const void* __restrict__ bv, long off,
                                                 const float* __restrict__ scal) {
  __shared__ float red[256];
  bool bf = scal[16] != 0.f;
  int row = blockIdx.x, t = threadIdx.x;
  size_t base = (size_t)row * 1024;
  int d = 4 * t;
  float4 cv = *(const float4*)&cellsB[base + d];
  float4 pv = *(const float4*)&proj[base + d];
  float v0 = cv.x + pv.x, v1 = cv.y + pv.y, v2 = cv.z + pv.z, v3 = cv.w + pv.w;
  red[t] = v0 + v1 + v2 + v3; __syncthreads();
  for (int o = 128; o; o >>= 1) { if (t < o) red[t] += red[t + o]; __syncthreads(); }
  float mu = red[0] * (1.f / 1024.f);
  __syncthreads();
  float d0 = v0 - mu, d1 = v1 - mu, d2 = v2 - mu, d3 = v3 - mu;
  red[t] = d0 * d0 + d1 * d1 + d2 * d2 + d3 * d3; __syncthreads();
  for (int o = 128; o; o >>= 1) { if (t < o) red[t] += red[t + o]; __syncthreads(); }
  float rstd = rsqrtf(red[0] * (1.f / 1024.f) + 1e-5f);
  float4 out;
  out.x = d0 * rstd * ldv(gv, off + d, bf)     + ldv(bv, off + d, bf);
  out.y = d1 * rstd * ldv(gv, off + d + 1, bf) + ldv(bv, off + d + 1, bf);
  out.z = d2 * rstd * ldv(gv, off + d + 2, bf) + ldv(bv, off + d + 2, bf);
  out.w = d3 * rstd * ldv(gv, off + d + 3, bf) + ldv(bv, off + d + 3, bf);
  *(float4*)&cellsB[base + d] = out;
  ushort4 ob;
  ob.x = f2bf(out.x); ob.y = f2bf(out.y); ob.z = f2bf(out.z); ob.w = f2bf(out.w);
  *(ushort4*)&cellsB16[base + d] = ob;
}

// ---------- tension finalize ----------
__global__ void tension_kernel(const float* __restrict__ scal, void* __restrict__ out) {
  bool bf = scal[16] != 0.f;
  float cnt = 8388608.f;
  float ten = 0.f;
  for (int l = 0; l < 2; ++l) {
    float v = scal[8 + l] / (cnt - 1.f);
    ten += sqrtf(fmaxf(v, 0.f));
  }
  ten *= 0.5f;
  if (bf) ((U16*)out)[2097152] = f2bf(ten);
  else    ((float*)out)[2097152] = ten;
}

extern "C" void kernel_launch(void* const* d_in, const int* in_sizes, int n_in,
                              void* d_out, int out_size, void* d_ws, size_t ws_size,
                              hipStream_t stream) {
  const void* X    = d_in[0];
  const void* AR   = d_in[1];
  const void* AI   = d_in[2];
  const void* CRc  = d_in[3];
  const void* CIc  = d_in[4];
  const void* CE   = d_in[5];
  const void* FS   = d_in[6];
  const void* WIN  = d_in[7];
  const void* BIN  = d_in[8];
  const void* AIW  = d_in[9];
  const void* AIB  = d_in[10];
  const void* AOW  = d_in[11];
  const void* AOB  = d_in[12];
  const void* LNG  = d_in[13];
  const void* LNB  = d_in[14];
  const void* WOUT = d_in[15];
  const void* BOUT = d_in[16];
  const int* STEP  = (const int*)d_in[17];

  // ws layout (float offsets), total ~75.6 MB (unchanged)
  float* ws = (float*)d_ws;
  float* scal  = ws;                  // 64
  float* probs = ws + 64;
  float* ph    = ws + 64 + 2048;
  float* fmean = ws + 64 + 4096;
  float* xp    = ws + 64 + 12288;
  float* cells = ws + 16384;           // 2M f (dead after cellsB_kernel -> reused as Vp)
  float* CB    = ws + 16384 + 2097152; // 16.78M f region
  // phase 1:
  float* ar = CB;
  float* ai = CB + 4194304;
  float* cr = CB + 8388608;
  float* ci = CB + 12582912;
  // phase 2 (aliases phase 1):
  float* cellsB   = CB;                                   // [0 .. 4M)
  U16*   qkv16    = (U16*)(CB + 4194304);                 // [4M .. 10.49M) x U16; K/V stripes dead after pack -> O half1
  float* proj     = CB + 4194304;                         // aliases dead qkv
  float* O32a     = CB + 10485760;                        // [10.49 .. 14.68M) f32 partial O half0
  U16*   cellsB16 = (U16*)(CB + 12582912);                // rebuilt by ln each layer (dead during attn)
  U16*   Kp       = (U16*)(CB + 14680064);                // [14.68 .. 16.78M) = 4M U16; after attn reused as O16
  U16*   Vp       = (U16*)cells;                          // cells region dead in phase 2: 4M U16
  U16*   O16      = Kp;                                   // bf16 normalized O (Kp dead post-attn)
  float* zg       = (float*)d_out;                        // scratch: z[32768] + G[262144]
  U16*   Wd16     = (U16*)d_out;                          // per-phase bf16 weight scratch (AIW: before zg; AOW: after gram_fin)
  U16*   WOUT16   = (U16*)proj;                           // proj dead after last ln

  init_kernel<<<1, 256, 0, stream>>>(X, (const U16*)LNG, scal);

  for (int w = 0; w < 2; ++w) {
    if (w == 0) walk_coined_kernel<<<8192, 256, 0, stream>>>(AR, AI, cr, ci, CRc, CIc, scal, 0);
    else        walk_coined_kernel<<<8192, 256, 0, stream>>>(ar, ai, cr, ci, CRc, CIc, scal, 1);
    walk_new_stats_kernel<<<2048, 256, 0, stream>>>(cr, ci, ar, ai, scal, scal, 1 + w, probs, ph);
    inject_cells_kernel<<<4096, 256, 0, stream>>>(w == 0 ? CE : (const void*)cells, cells,
                                                  probs, ph, scal, 1 + w, w == 0 ? 1 : 0);
  }
  frustration_kernel<<<1024, 64, 0, stream>>>(cells, FS, scal);
  standing_kernel<<<8192, 256, 0, stream>>>(cells, STEP);
  morphism_kernel<<<1024, 64, 0, stream>>>(cells, STEP);
  faction_mean_kernel<<<32, 256, 0, stream>>>(cells, fmean);
  faction_apply_kernel<<<8192, 256, 0, stream>>>(cells, fmean, STEP);

  xproj_kernel<<<8, 256, 0, stream>>>(X, WIN, BIN, xp, scal);
  cellsB_kernel<<<16384, 256, 0, stream>>>(cells, xp, cellsB, cellsB16);
  // cells region now dead -> Vp

  for (int l = 0; l < 2; ++l) {
    // AIW bf16 into d_out scratch (dead until zero_zg)
    wcvt_kernel<<<3072, 256, 0, stream>>>(AIW, (long)l * 3072 * 1024, Wd16, 786432, scal);
    mfma_gemm_kernel<<<dim3(24, 32), 256, 0, stream>>>(cellsB16, AIW, (long)l * 3072 * 1024, Wd16,
                                                       AIB, (long)l * 3072, qkv16, 3072, 1, scal);
    pack_kv_kernel<<<dim3(32, 16, 2), 256, 0, stream>>>(qkv16, Kp, Vp);
    zero_zg_kernel<<<1152, 256, 0, stream>>>(zg);
    attn_mfma_kernel<<<256, 512, 0, stream>>>(qkv16, Kp, Vp, O32a, zg);
    attn_norm_kernel<<<4096, 256, 0, stream>>>(O32a, qkv16, zg, O16);
    gram_fin_kernel<<<64, 256, 0, stream>>>(zg, scal, 8 + l);
    // AOW bf16 into d_out scratch (zg dead after gram_fin)
    wcvt_kernel<<<1024, 256, 0, stream>>>(AOW, (long)l * 1024 * 1024, Wd16, 262144, scal);
    mfma_gemm_kernel<<<dim3(8, 32), 256, 0, stream>>>(O16, AOW, (long)l * 1024 * 1024, Wd16,
                                                      AOB, (long)l * 1024, proj, 1024, 0, scal);
    ln_kernel<<<4096, 256, 0, stream>>>(cellsB, cellsB16, proj, LNG, LNB, (long)l * 1024, scal);
  }
  // WOUT bf16 into dead proj region (final gemm writes d_out)
  wcvt_kernel<<<512, 256, 0, stream>>>(WOUT, 0, WOUT16, 131072, scal);
  mfma_gemm_kernel<<<dim3(4, 32), 256, 0, stream>>>(cellsB16, WOUT, 0, WOUT16,
                                                    BOUT, 0, d_out, 512, 2, scal);
  tension_kernel<<<1, 1, 0, stream>>>(scal, d_out);
}

// Round 6
// 766.279 us; speedup vs baseline: 1.3020x; 1.0255x over previous
//
#include <hip/hip_runtime.h>

#define U16 unsigned short

typedef short bf16x8 __attribute__((ext_vector_type(8)));
typedef float f32x4 __attribute__((ext_vector_type(4)));

// ---------- bf16 helpers ----------
__device__ __forceinline__ float bfp(const U16* p) { return __uint_as_float(((unsigned)(*p)) << 16); }
__device__ __forceinline__ U16 f2bf(float f) {
  unsigned u = __float_as_uint(f);
  u += 0x7FFFu + ((u >> 16) & 1u);
  return (U16)(u >> 16);
}
__device__ __forceinline__ float ldv(const void* p, long i, bool bf) {
  return bf ? bfp((const U16*)p + i) : ((const float*)p)[i];
}
// async global->LDS, 16B per lane; LDS dest is wave-uniform base (+lane*16 by HW),
// global src is per-lane (pre-swizzled to match fragment-major layout).
__device__ __forceinline__ void gload_lds16(const U16* g, U16* l) {
  __builtin_amdgcn_global_load_lds((const __attribute__((address_space(1))) void*)g,
                                   (__attribute__((address_space(3))) void*)l, 16, 0, 0);
}

// scal slots: 0=x_mean, 1..2=walk norms (S_raw, == raw prob sums), 8..9=tension Sq, 16=bf16 flag

// ---------- init: dtype detect + x_mean + zero scalar slab ----------
__global__ __launch_bounds__(256) void init_kernel(const void* __restrict__ x, const U16* __restrict__ lng,
                                                   float* __restrict__ scal) {
  __shared__ float red[256];
  __shared__ int fl;
  int t = threadIdx.x;
  if (t == 0) fl = (lng[0] != 0) ? 1 : 0;   // ln_g==1.0: bf16 -> 0x3F80, fp32 low half -> 0x0000
  __syncthreads();
  bool bf = fl != 0;
  float s = 0.f;
  for (int i = t; i < 1024; i += 256) s += ldv(x, i, bf);
  red[t] = s; __syncthreads();
  for (int o = 128; o; o >>= 1) { if (t < o) red[t] += red[t + o]; __syncthreads(); }
  if (t == 0) { scal[0] = red[0] * (1.f / 1024.f); scal[16] = bf ? 1.f : 0.f; }
  else if (t < 64 && t != 16) scal[t] = 0.f;
}

// ---------- quantum walk: coined ----------
__global__ __launch_bounds__(256) void walk_coined_kernel(const void* __restrict__ arv, const void* __restrict__ aiv,
                                                          float* __restrict__ cr, float* __restrict__ ci,
                                                          const void* __restrict__ coinR, const void* __restrict__ coinI,
                                                          const float* __restrict__ scal, int iter) {
  bool bf = scal[16] != 0.f;
  int id = blockIdx.x * 256 + threadIdx.x;   // (n,d): 2048*1024
  int n = id >> 10, d = id & 1023;
  size_t b0 = (size_t)n * 2048 + d;
  float pre = 1.f;
  float a0r, a0i, a1r, a1i;
  if (iter == 0) {
    a0r = ldv(arv, b0, bf); a1r = ldv(arv, b0 + 1024, bf);
    a0i = ldv(aiv, b0, bf); a1i = ldv(aiv, b0 + 1024, bf);
  } else {
    pre = 1.f / (sqrtf(scal[iter]) + 1e-8f);
    const float* ar = (const float*)arv;
    const float* ai = (const float*)aiv;
    a0r = ar[b0]; a1r = ar[b0 + 1024]; a0i = ai[b0]; a1i = ai[b0 + 1024];
  }
  a0r *= pre; a0i *= pre; a1r *= pre; a1i *= pre;
  float c00r = ldv(coinR, 0, bf), c01r = ldv(coinR, 1, bf), c10r = ldv(coinR, 2, bf), c11r = ldv(coinR, 3, bf);
  float c00i = ldv(coinI, 0, bf), c01i = ldv(coinI, 1, bf), c10i = ldv(coinI, 2, bf), c11i = ldv(coinI, 3, bf);
  cr[b0]        = c00r * a0r - c00i * a0i + c01r * a1r - c01i * a1i;
  ci[b0]        = c00r * a0i + c00i * a0r + c01r * a1i + c01i * a1r;
  cr[b0 + 1024] = c10r * a0r - c10i * a0i + c11r * a1r - c11i * a1i;
  ci[b0 + 1024] = c10r * a0i + c10i * a0r + c11r * a1i + c11i * a1r;
}

// ---------- fused walk_new + inject_stats ----------
__global__ __launch_bounds__(256) void walk_new_stats_kernel(const float* __restrict__ cr, const float* __restrict__ ci,
                                                             float* __restrict__ ar, float* __restrict__ ai,
                                                             const float* __restrict__ scal, float* __restrict__ scalw,
                                                             int slot, float* __restrict__ probs, float* __restrict__ ph) {
  __shared__ float r1[256], r2[256];
  int n = blockIdx.x, t = threadIdx.x;
  float th = scal[0] * 0.1f;
  float sn, cs; sincosf(th, &sn, &cs);
  float pacc = 0.f, phacc = 0.f;
  #pragma unroll
  for (int it = 0; it < 4; ++it) {
    int d = t + it * 256;
    size_t b0 = (size_t)n * 2048 + d;
    float n0r = cr[b0], n0i = ci[b0];
    float s1r = 0.f, s1i = 0.f;
    #pragma unroll
    for (int k = 0; k < 11; ++k) {
      size_t j = (size_t)(n ^ (1 << k)) * 2048 + 1024 + d;
      s1r += cr[j]; s1i += ci[j];
    }
    s1r *= (1.f / 11.f); s1i *= (1.f / 11.f);
    float o0r = n0r * cs - n0i * sn, o0i = n0r * sn + n0i * cs;
    float o1r = s1r * cs - s1i * sn, o1i = s1r * sn + s1i * cs;
    ar[b0] = o0r; ai[b0] = o0i; ar[b0 + 1024] = o1r; ai[b0 + 1024] = o1i;
    pacc += o0r * o0r + o0i * o0i + o1r * o1r + o1i * o1i;
    phacc += atan2f(o0i + o1i, o0r + o1r);
  }
  r1[t] = pacc; r2[t] = phacc; __syncthreads();
  for (int o = 128; o; o >>= 1) { if (t < o) { r1[t] += r1[t + o]; r2[t] += r2[t + o]; } __syncthreads(); }
  if (t == 0) { probs[n] = r1[0]; ph[n] = r2[0] * (1.f / 1024.f); atomicAdd(&scalw[slot], r1[0]); }
}

// ---------- inject ----------
__global__ __launch_bounds__(256) void inject_cells_kernel(const void* __restrict__ cellsIn, float* __restrict__ cells,
                                                           const float* __restrict__ probs,
                                                           const float* __restrict__ ph, const float* __restrict__ scal,
                                                           int wslot, int useRaw) {
  bool bf = scal[16] != 0.f;
  int id = blockIdx.x * 256 + threadIdx.x;   // 2048*512
  int c = id >> 9, d = id & 511;
  float invn = 1.f / (sqrtf(scal[wslot]) + 1e-8f);
  float inv2 = invn * invn;
  float denom = 1.f / (scal[wslot] * inv2 + 1e-8f);
  float psc = inv2 * denom;
  float p = probs[c] * psc;
  float interf = 0.f;
  #pragma unroll
  for (int j = 0; j < 6; ++j) interf += (p - probs[c ^ (1 << j)] * psc);
  interf *= 0.03f;
  float scale = 0.8f + 0.4f * p;
  float phc = ph[c] * 0.3f;
  float sn, cs; sincosf(phc, &sn, &cs);
  size_t base = (size_t)c * 1024 + d;
  float h1, h2;
  if (useRaw) { h1 = ldv(cellsIn, base, bf) * scale; h2 = ldv(cellsIn, base + 512, bf) * scale; }
  else        { h1 = cells[base] * scale;            h2 = cells[base + 512] * scale; }
  float r1 = h1 * cs - h2 * sn, r2 = h1 * sn + h2 * cs;
  cells[base]       = 0.5f * (r1 + h1) + interf;
  cells[base + 512] = 0.5f * (r2 + h2) + interf;
}

// ---------- frustration: one wave per column, rows in registers, shuffle chain ----------
__global__ __launch_bounds__(64) void frustration_kernel(float* __restrict__ cells, const void* __restrict__ fs,
                                                         const float* __restrict__ scal) {
  bool bf = scal[16] != 0.f;
  int d = blockIdx.x;      // 1024 columns
  int l = threadIdx.x;     // 64 lanes
  float s0 = ldv(fs, l, bf);
  float s1 = ldv(fs, l + 64, bf);
  float w0 = s0 * cells[(size_t)l * 1024 + d];
  float w1 = s1 * cells[(size_t)(l + 64) * 1024 + d];
  float stat0 = 0.f, stat1 = 0.f;
  #pragma unroll
  for (int b = 7; b < 10; ++b) {
    int j0 = l ^ (1 << b);
    int j1 = (l + 64) ^ (1 << b);
    stat0 += ldv(fs, j0, bf) * cells[(size_t)j0 * 1024 + d];
    stat1 += ldv(fs, j1, bf) * cells[(size_t)j1 * 1024 + d];
  }
  #pragma unroll
  for (int i = 0; i < 128; ++i) {
    const int hi = i >> 6;
    const int li = i & 63;
    float vsrc = (hi == 0) ? w0 : w1;
    float voth = (hi == 0) ? w1 : w0;
    float acc = __shfl(vsrc, li ^ 1) + __shfl(vsrc, li ^ 2) + __shfl(vsrc, li ^ 4)
              + __shfl(vsrc, li ^ 8) + __shfl(vsrc, li ^ 16) + __shfl(vsrc, li ^ 32)
              + __shfl(voth, li);
    if (l == li) {
      if (hi == 0) w0 = 0.85f * w0 + 0.015f * (acc + stat0);
      else         w1 = 0.85f * w1 + 0.015f * (acc + stat1);
    }
  }
  cells[(size_t)l * 1024 + d]        = s0 * w0;
  cells[(size_t)(l + 64) * 1024 + d] = s1 * w1;
}

// ---------- standing wave ----------
__global__ __launch_bounds__(256) void standing_kernel(float* __restrict__ cells, const int* __restrict__ stepp) {
  int id = blockIdx.x * 256 + threadIdx.x;   // 2M
  int c = id >> 10;
  float st = (float)stepp[0] * 0.15f;
  float fwd = fmodf(st, 2048.f);
  float bwd = fmodf(2048.f - st, 2048.f);
  float fi = (float)c;
  float r1 = 1.f / coshf((fi - fwd) * 0.5f);
  float r2 = 1.f / coshf((fi - bwd) * 0.5f);
  cells[id] *= (1.f + 0.03f * (r1 * r1 + r2 * r2));
}

// ---------- morphism: one wave per column, rows in registers, shuffle reduce ----------
__global__ __launch_bounds__(64) void morphism_kernel(float* __restrict__ cells, const int* __restrict__ stepp) {
  if (stepp[0] % 3 != 0) return;
  int d = blockIdx.x;        // 1024 columns
  int l = threadIdx.x;       // 64 lanes, 0..47 active
  float v = 0.f;
  if (l < 48) v = cells[(size_t)l * 1024 + d];
  for (int i = 0; i < 48; ++i) {
    float vi = __shfl(v, i);
    float x = v - vi;
    float e2 = __expf(2.f * x);
    float th = (l < 48) ? (1.f - 2.f / (e2 + 1.f)) : 0.f;
    th += __shfl_xor(th, 1);
    th += __shfl_xor(th, 2);
    th += __shfl_xor(th, 4);
    th += __shfl_xor(th, 8);
    th += __shfl_xor(th, 16);
    th += __shfl_xor(th, 32);
    if (l == i) v = 0.9f * v + (0.1f / 47.f) * th;
  }
  if (l < 48) cells[(size_t)l * 1024 + d] = v;
}

// ---------- faction ----------
__global__ __launch_bounds__(256) void faction_mean_kernel(const float* __restrict__ cells, float* __restrict__ fmean) {
  int id = blockIdx.x * 256 + threadIdx.x;   // 8*1024
  int f = id >> 10, d = id & 1023;
  float s = 0.f;
  for (int r = 0; r < 256; ++r) s += cells[(size_t)((f << 8) + r) * 1024 + d];
  fmean[id] = s * (1.f / 256.f);
}
__global__ __launch_bounds__(256) void faction_apply_kernel(float* __restrict__ cells, const float* __restrict__ fmean,
                                                            const int* __restrict__ stepp) {
  int id = blockIdx.x * 256 + threadIdx.x;   // 2M
  int c = id >> 10, d = id & 1023;
  int f = c >> 8, r = c & 255;
  float v = 0.85f * cells[id] + 0.15f * fmean[f * 1024 + d];
  if (stepp[0] > 5 && r < 64) {
    float g = 0.f;
    #pragma unroll
    for (int ff = 0; ff < 8; ++ff) g += fmean[ff * 1024 + d];
    v = 0.85f * v + 0.15f * g * 0.125f;
  }
  cells[id] = v;
}

// ---------- x projection ----------
__global__ __launch_bounds__(256) void xproj_kernel(const void* __restrict__ x, const void* __restrict__ w_in,
                                                    const void* __restrict__ b_in, float* __restrict__ xp,
                                                    const float* __restrict__ scal) {
  bool bf = scal[16] != 0.f;
  int id = blockIdx.x * 256 + threadIdx.x;   // 2048
  int b = id >> 10, o = id & 1023;
  float acc = ldv(b_in, o, bf);
  if (bf) {
    const U16* xr = (const U16*)x + b * 512;
    const U16* wr = (const U16*)w_in + (long)o * 512;
    for (int k = 0; k < 512; ++k) acc += bfp(xr + k) * bfp(wr + k);
  } else {
    const float* xr = (const float*)x + b * 512;
    const float* wr = (const float*)w_in + (long)o * 512;
    for (int k = 0; k < 512; ++k) acc += xr[k] * wr[k];
  }
  xp[id] = acc;
}

// writes fp32 cellsB + bf16 mirror
__global__ __launch_bounds__(256) void cellsB_kernel(const float* __restrict__ cells, const float* __restrict__ xp,
                                                     float* __restrict__ cellsB, U16* __restrict__ cellsB16) {
  int id = blockIdx.x * 256 + threadIdx.x;   // 4M
  int b = id >> 21;
  int cd = id & ((1 << 21) - 1);
  int d = id & 1023;
  float v = cells[cd] + 0.1f * xp[(b << 10) + d];
  cellsB[id] = v;
  cellsB16[id] = f2bf(v);
}

// ---------- weight pre-convert f32 -> bf16 (no-op when inputs already bf16) ----------
__global__ __launch_bounds__(256) void wcvt_kernel(const void* __restrict__ W, long off,
                                                   U16* __restrict__ dst, int n4,
                                                   const float* __restrict__ scal) {
  if (scal[16] != 0.f) return;   // bf16 inputs: gemm reads original weights directly
  int id = blockIdx.x * 256 + threadIdx.x;
  if (id < n4) {
    const float* src = (const float*)W + off;
    float4 v = *(const float4*)&src[(size_t)id * 4];
    ushort4 o;
    o.x = f2bf(v.x); o.y = f2bf(v.y); o.z = f2bf(v.z); o.w = f2bf(v.w);
    *(ushort4*)&dst[(size_t)id * 4] = o;
  }
}

// ---------- MFMA GEMM: C[M,N] = A[M,1024](bf16) * W[N,1024]^T + bias ----------
__global__ __launch_bounds__(256) void mfma_gemm_kernel(const U16* __restrict__ A16,
                                                        const void* __restrict__ Wv, long Woff,
                                                        const U16* __restrict__ W16s,
                                                        const void* __restrict__ biasv, long Boff,
                                                        void* __restrict__ Cout, int N, int mode,
                                                        const float* __restrict__ scal) {
  __shared__ U16 Al[4096];
  __shared__ U16 Wl[4096];
  bool bf = scal[16] != 0.f;
  const int K = 1024;
  int t = threadIdx.x;
  int wv = t >> 6, l = t & 63;
  int n0 = blockIdx.x * 128, m0 = blockIdx.y * 128;
  int wmt = (wv & 1) * 4;
  int wnt = (wv >> 1) * 4;
  const U16* Wb = bf ? (const U16*)Wv + Woff : W16s;

  int fr0 = wv * 2, fr1 = fr0 + 1;
  const U16* asrc0 = A16 + (size_t)(m0 + fr0 * 16 + (l & 15)) * K + (l >> 4) * 8;
  const U16* asrc1 = A16 + (size_t)(m0 + fr1 * 16 + (l & 15)) * K + (l >> 4) * 8;
  const U16* wsrc0 = Wb  + (size_t)(n0 + fr0 * 16 + (l & 15)) * K + (l >> 4) * 8;
  const U16* wsrc1 = Wb  + (size_t)(n0 + fr1 * 16 + (l & 15)) * K + (l >> 4) * 8;
  U16* adst0 = &Al[fr0 * 512];
  U16* adst1 = &Al[fr1 * 512];
  U16* wdst0 = &Wl[fr0 * 512];
  U16* wdst1 = &Wl[fr1 * 512];

  f32x4 acc[4][4];
  #pragma unroll
  for (int i = 0; i < 4; ++i)
    #pragma unroll
    for (int j = 0; j < 4; ++j) acc[i][j] = (f32x4){0.f, 0.f, 0.f, 0.f};

  for (int k0 = 0; k0 < K; k0 += 32) {
    __syncthreads();
    gload_lds16(asrc0 + k0, adst0);
    gload_lds16(asrc1 + k0, adst1);
    gload_lds16(wsrc0 + k0, wdst0);
    gload_lds16(wsrc1 + k0, wdst1);
    __syncthreads();
    bf16x8 afr[4], bfr[4];
    #pragma unroll
    for (int i = 0; i < 4; ++i) afr[i] = *(const bf16x8*)&Al[((wmt + i) * 64 + l) * 8];
    #pragma unroll
    for (int j = 0; j < 4; ++j) bfr[j] = *(const bf16x8*)&Wl[((wnt + j) * 64 + l) * 8];
    #pragma unroll
    for (int i = 0; i < 4; ++i)
      #pragma unroll
      for (int j = 0; j < 4; ++j)
        acc[i][j] = __builtin_amdgcn_mfma_f32_16x16x32_bf16(afr[i], bfr[j], acc[i][j], 0, 0, 0);
  }
  bool outBf = (mode == 1) || (mode == 2 && bf);
  int cl = l & 15, rq = l >> 4;
  #pragma unroll
  for (int j = 0; j < 4; ++j) {
    int n = n0 + (wnt + j) * 16 + cl;
    float bv = ldv(biasv, Boff + n, bf);
    #pragma unroll
    for (int i = 0; i < 4; ++i) {
      int mrow = m0 + (wmt + i) * 16 + rq * 4;
      #pragma unroll
      for (int r = 0; r < 4; ++r) {
        float v = acc[i][j][r] + bv;
        if (outBf) ((U16*)Cout)[(size_t)(mrow + r) * N + n] = f2bf(v);
        else       ((float*)Cout)[(size_t)(mrow + r) * N + n] = v;
      }
    }
  }
}

// ---------- fused pack of K and V into fragment-major streams ----------
__global__ __launch_bounds__(256) void pack_kv_kernel(const U16* __restrict__ qkv,
                                                      U16* __restrict__ Kp, U16* __restrict__ Vp) {
  __shared__ U16 tile[64][132];
  int t = threadIdx.x;
  int kc = blockIdx.x, bh = blockIdx.y;
  int b = bh >> 3, h = bh & 7;
  size_t dstB = ((size_t)bh * 32 + kc) * 8192;
  if (blockIdx.z == 0) {
    int w = t >> 6, l = t & 63;
    int l16 = l & 15, quad = l >> 4;
    #pragma unroll
    for (int fi = 0; fi < 4; ++fi) {
      int f = w * 4 + fi;
      int nt = f >> 2, kf = f & 3;
      const U16* src = qkv + ((size_t)(b * 2048 + kc * 64 + nt * 16 + l16)) * 3072 + 1024 + h * 128 + kf * 32 + quad * 8;
      *(uint4*)(Kp + dstB + (size_t)f * 512 + l * 8) = *(const uint4*)src;
    }
  } else {
    int r = t >> 2, c0 = (t & 3) * 32;
    const U16* src = qkv + ((size_t)(b * 2048 + kc * 64 + r)) * 3072 + 2048 + h * 128 + c0;
    #pragma unroll
    for (int q = 0; q < 8; ++q)
      *(ushort4*)&tile[r][c0 + q * 4] = *(const ushort4*)(src + q * 4);
    __syncthreads();
    #pragma unroll
    for (int i = 0; i < 4; ++i) {
      int p = t + 256 * i;
      int g = p >> 6, l = p & 63;
      int l16 = l & 15, quad = l >> 4;
      int nt = g >> 1, kf = g & 1;
      U16 vals[8];
      #pragma unroll
      for (int j = 0; j < 8; ++j) vals[j] = tile[kf * 32 + quad * 8 + j][nt * 16 + l16];
      *(uint4*)(Vp + dstB + (size_t)g * 512 + l * 8) = *(const uint4*)vals;
    }
  }
}

// ---------- zero z+G scratch (in d_out) ----------
__global__ __launch_bounds__(256) void zero_zg_kernel(float* __restrict__ zg) {
  int id = blockIdx.x * 256 + threadIdx.x;
  if (id < 294912) zg[id] = 0.f;
}

// ---------- MFMA fused attention: producer-consumer wave specialization ----------
// R5 post-mortem: 2 waves/SIMD (unified regs ~215/wave) left ~55% stall. Split roles:
// 8 QK waves (afr+bK+sacc+z+gacc ~116 VGPR) produce e(c+1) into LDS buf (c+1)&1 and
// do Gram(c); 8 PV waves (bV+oacc ~111 VGPR) consume buf c&1 into O accumulators.
// Each role fits <=128 VGPR (__launch_bounds__(1024,4)) -> 4 waves/SIMD co-resident.
// One barrier per chunk; double-buffered e; 32 q-rows/block; k-split x2; grid 256.
#define EHST 1040          // per-head e-region stride (U16): 2 subs * 512 + pad
#define EBST (8 * EHST)    // per-buffer stride
__global__ __launch_bounds__(1024, 4) void attn_mfma_kernel(U16* __restrict__ qkv,
                                                            const U16* __restrict__ Kp, const U16* __restrict__ Vp,
                                                            float* __restrict__ O32a,
                                                            float* __restrict__ zg) {
  __shared__ U16 ebuf[2 * EBST];
  int t = threadIdx.x;
  int w16 = t >> 6;        // 0..15
  int h = w16 & 7;         // head for this wave
  int l = t & 63;
  int l16 = l & 15, quad = l >> 4;
  int idx = blockIdx.x;
  int khalf = idx & 1;
  int b = (idx >> 1) & 1;
  int q0 = (idx >> 2) * 32;
  size_t rowB = (size_t)b * 2048;
  const float sc = 0.08838834764831845f;
  const int c0 = khalf * 32, cend = c0 + 32;   // 32-row chunks, 64 total over k=2048

  if (w16 < 8) {
    // ================= QK + Gram role =================
    const U16* KpB = Kp + (size_t)(b * 8 + h) * 262144;
    bf16x8 afr[2][4];
    #pragma unroll
    for (int s = 0; s < 2; ++s) {
      const U16* Qb = qkv + (rowB + q0 + s * 16 + l16) * 3072 + h * 128 + quad * 8;
      #pragma unroll
      for (int kf = 0; kf < 4; ++kf) afr[s][kf] = *(const bf16x8*)(Qb + kf * 32);
    }
    f32x4 gacc[2];
    gacc[0] = (f32x4){0.f, 0.f, 0.f, 0.f};
    gacc[1] = (f32x4){0.f, 0.f, 0.f, 0.f};
    float zacc[2][4] = {{0.f, 0.f, 0.f, 0.f}, {0.f, 0.f, 0.f, 0.f}};
    bf16x8 bK[2][4];

    auto kload = [&](int c) {
      int kc64 = c >> 1, nh = (c & 1) * 2;
      #pragma unroll
      for (int i = 0; i < 2; ++i)
        #pragma unroll
        for (int kf = 0; kf < 4; ++kf)
          bK[i][kf] = *(const bf16x8*)(KpB + (size_t)kc64 * 8192 + (size_t)((nh + i) * 4 + kf) * 512 + l * 8);
    };
    auto produce = [&](int c) {   // QK + exp + e-store for chunk c (uses current bK)
      f32x4 sacc[2][2];
      #pragma unroll
      for (int s = 0; s < 2; ++s)
        #pragma unroll
        for (int i = 0; i < 2; ++i) {
          sacc[s][i] = (f32x4){0.f, 0.f, 0.f, 0.f};
          #pragma unroll
          for (int kf = 0; kf < 4; ++kf)
            sacc[s][i] = __builtin_amdgcn_mfma_f32_16x16x32_bf16(afr[s][kf], bK[i][kf], sacc[s][i], 0, 0, 0);
        }
      U16* eb = &ebuf[(c & 1) * EBST + h * EHST];
      #pragma unroll
      for (int s = 0; s < 2; ++s) {
        #pragma unroll
        for (int i = 0; i < 2; ++i) {
          int kq = i * 2 + (l16 >> 3);
          int j = l16 & 7;
          #pragma unroll
          for (int r = 0; r < 4; ++r) {
            float e = __expf(fminf(sacc[s][i][r] * sc, 30.f));
            zacc[s][r] += e;
            eb[s * 512 + kq * 128 + (quad * 4 + r) * 8 + j] = f2bf(e);
          }
        }
      }
    };

    kload(c0);
    produce(c0);                       // chunk c0 -> buf c0&1 (visible after first barrier)
    if (c0 + 1 < cend) kload(c0 + 1);

    for (int c = c0; c < cend; ++c) {
      __syncthreads();                 // buf c&1 complete for all heads
      if (c + 1 < cend) {
        produce(c + 1);                // -> buf (c+1)&1 (other buffer)
        if (c + 2 < cend) kload(c + 2);
      }
      // Gram(c): all-head e from buf c&1; this wave covers q-pair h*2+{0,1}
      const U16* gb = &ebuf[(c & 1) * EBST];
      #pragma unroll
      for (int s = 0; s < 2; ++s) {
        bf16x8 gfr = *(const bf16x8*)(gb + (size_t)(l & 7) * EHST + s * 512
                                      + (quad * 16 + h * 2 + ((l >> 3) & 1)) * 8);
        gacc[s] = __builtin_amdgcn_mfma_f32_16x16x32_bf16(gfr, gfr, gacc[s], 0, 0, 0);
      }
    }
    // z butterfly + atomics
    #pragma unroll
    for (int s = 0; s < 2; ++s)
      #pragma unroll
      for (int r = 0; r < 4; ++r) {
        float z = zacc[s][r];
        z += __shfl_xor(z, 1); z += __shfl_xor(z, 2);
        z += __shfl_xor(z, 4); z += __shfl_xor(z, 8);
        zacc[s][r] = z;
      }
    if (l16 == 0) {
      #pragma unroll
      for (int s = 0; s < 2; ++s)
        #pragma unroll
        for (int r = 0; r < 4; ++r) {
          size_t m = rowB + q0 + s * 16 + quad * 4 + r;
          atomicAdd(&zg[m * 8 + h], zacc[s][r]);
        }
    }
    // Gram partials: valid entries have m-parity == n-parity
    {
      int h2 = l16 & 7, b2 = l16 >> 3;
      int a = quad >> 1;
      if (a == b2) {
        float* G = zg + 32768;
        #pragma unroll
        for (int s = 0; s < 2; ++s) {
          size_t m = rowB + q0 + s * 16 + h * 2 + a;
          #pragma unroll
          for (int r = 0; r < 4; ++r) {
            int h1 = (quad * 4 + r) & 7;
            atomicAdd(&G[m * 64 + h1 * 8 + h2], gacc[s][r]);
          }
        }
      }
    }
  } else {
    // ================= PV role =================
    const U16* VpB = Vp + (size_t)(b * 8 + h) * 262144;
    f32x4 oacc[2][8];
    #pragma unroll
    for (int s = 0; s < 2; ++s)
      #pragma unroll
      for (int i = 0; i < 8; ++i) oacc[s][i] = (f32x4){0.f, 0.f, 0.f, 0.f};
    bf16x8 bV[8];

    auto vload = [&](int c) {
      int kc64 = c >> 1, vk = c & 1;
      #pragma unroll
      for (int nt = 0; nt < 8; ++nt)
        bV[nt] = *(const bf16x8*)(VpB + (size_t)kc64 * 8192 + (size_t)(nt * 2 + vk) * 512 + l * 8);
    };

    vload(c0);
    for (int c = c0; c < cend; ++c) {
      __syncthreads();                 // e(c) ready in buf c&1
      const U16* eb = &ebuf[(c & 1) * EBST + h * EHST];
      #pragma unroll
      for (int s = 0; s < 2; ++s) {
        bf16x8 pfr = *(const bf16x8*)&eb[s * 512 + l * 8];
        #pragma unroll
        for (int nt = 0; nt < 8; ++nt)
          oacc[s][nt] = __builtin_amdgcn_mfma_f32_16x16x32_bf16(pfr, bV[nt], oacc[s][nt], 0, 0, 0);
      }
      if (c + 1 < cend) vload(c + 1);
    }
    // O partial store (unnormalized f32)
    #pragma unroll
    for (int s = 0; s < 2; ++s)
      #pragma unroll
      for (int r = 0; r < 4; ++r) {
        size_t m = rowB + q0 + s * 16 + quad * 4 + r;
        float* orow;
        if (khalf == 0) orow = O32a + m * 1024 + h * 128 + l16;
        else            orow = (float*)(qkv + m * 3072 + 1024) + h * 128 + l16;   // dead K/V stripe
        #pragma unroll
        for (int nt = 0; nt < 8; ++nt) orow[nt * 16] = oacc[s][nt][r];
      }
  }
}

// ---------- combine O halves + normalize by total z -> bf16 O16 ----------
__global__ __launch_bounds__(256) void attn_norm_kernel(const float* __restrict__ O32a, const U16* __restrict__ qkv,
                                                        const float* __restrict__ zg, U16* __restrict__ O16) {
  int id = blockIdx.x * 256 + threadIdx.x;   // 1048576 threads * 4 f32
  int base = id * 4;
  int m = base >> 10, d = base & 1023;
  const float* ob = (const float*)(qkv + (size_t)m * 3072 + 1024);
  float4 a = *(const float4*)&O32a[base];
  float4 bv = *(const float4*)&ob[d];
  float inv = 1.f / zg[m * 8 + (d >> 7)];
  ushort4 o;
  o.x = f2bf((a.x + bv.x) * inv);
  o.y = f2bf((a.y + bv.y) * inv);
  o.z = f2bf((a.z + bv.z) * inv);
  o.w = f2bf((a.w + bv.w) * inv);
  *(ushort4*)&O16[base] = o;
}

// ---------- gram finalize: sum G/(z1*z2)/64 - 2 into scal[slot] ----------
__global__ __launch_bounds__(256) void gram_fin_kernel(const float* __restrict__ zg, float* __restrict__ scal, int slot) {
  __shared__ float red[256];
  int t = threadIdx.x;
  const float* G = zg + 32768;
  float s = 0.f;
  for (int i = blockIdx.x * 256 * 16 + t; i < (blockIdx.x + 1) * 256 * 16; i += 256) {
    int m = i >> 6, h1 = (i >> 3) & 7, h2 = i & 7;
    s += G[i] / (zg[m * 8 + h1] * zg[m * 8 + h2]);
  }
  red[t] = s; __syncthreads();
  for (int o = 128; o; o >>= 1) { if (t < o) red[t] += red[t + o]; __syncthreads(); }
  if (t == 0) atomicAdd(&scal[slot], red[0] * (1.f / 64.f) - (blockIdx.x == 0 ? 2.0f : 0.0f));
}

// ---------- residual + LayerNorm (writes fp32 + bf16 mirror) ----------
__global__ __launch_bounds__(256) void ln_kernel(float* __restrict__ cellsB, U16* __restrict__ cellsB16,
                                                 const float* __restrict__ proj,
                                                 const void* __restrict__ gv, const void* __restrict__ bv, long off,
                                                 const float* __restrict__ scal) {
  __shared__ float red[256];
  bool bf = scal[16] != 0.f;
  int row = blockIdx.x, t = threadIdx.x;
  size_t base = (size_t)row * 1024;
  int d = 4 * t;
  float4 cv = *(const float4*)&cellsB[base + d];
  float4 pv = *(const float4*)&proj[base + d];
  float v0 = cv.x + pv.x, v1 = cv.y + pv.y, v2 = cv.z + pv.z, v3 = cv.w + pv.w;
  red[t] = v0 + v1 + v2 + v3; __syncthreads();
  for (int o = 128; o; o >>= 1) { if (t < o) red[t] += red[t + o]; __syncthreads(); }
  float mu = red[0] * (1.f / 1024.f);
  __syncthreads();
  float d0 = v0 - mu, d1 = v1 - mu, d2 = v2 - mu, d3 = v3 - mu;
  red[t] = d0 * d0 + d1 * d1 + d2 * d2 + d3 * d3; __syncthreads();
  for (int o = 128; o; o >>= 1) { if (t < o) red[t] += red[t + o]; __syncthreads(); }
  float rstd = rsqrtf(red[0] * (1.f / 1024.f) + 1e-5f);
  float4 out;
  out.x = d0 * rstd * ldv(gv, off + d, bf)     + ldv(bv, off + d, bf);
  out.y = d1 * rstd * ldv(gv, off + d + 1, bf) + ldv(bv, off + d + 1, bf);
  out.z = d2 * rstd * ldv(gv, off + d + 2, bf) + ldv(bv, off + d + 2, bf);
  out.w = d3 * rstd * ldv(gv, off + d + 3, bf) + ldv(bv, off + d + 3, bf);
  *(float4*)&cellsB[base + d] = out;
  ushort4 ob;
  ob.x = f2bf(out.x); ob.y = f2bf(out.y); ob.z = f2bf(out.z); ob.w = f2bf(out.w);
  *(ushort4*)&cellsB16[base + d] = ob;
}

// ---------- tension finalize ----------
__global__ void tension_kernel(const float* __restrict__ scal, void* __restrict__ out) {
  bool bf = scal[16] != 0.f;
  float cnt = 8388608.f;
  float ten = 0.f;
  for (int l = 0; l < 2; ++l) {
    float v = scal[8 + l] / (cnt - 1.f);
    ten += sqrtf(fmaxf(v, 0.f));
  }
  ten *= 0.5f;
  if (bf) ((U16*)out)[2097152] = f2bf(ten);
  else    ((float*)out)[2097152] = ten;
}

extern "C" void kernel_launch(void* const* d_in, const int* in_sizes, int n_in,
                              void* d_out, int out_size, void* d_ws, size_t ws_size,
                              hipStream_t stream) {
  const void* X    = d_in[0];
  const void* AR   = d_in[1];
  const void* AI   = d_in[2];
  const void* CRc  = d_in[3];
  const void* CIc  = d_in[4];
  const void* CE   = d_in[5];
  const void* FS   = d_in[6];
  const void* WIN  = d_in[7];
  const void* BIN  = d_in[8];
  const void* AIW  = d_in[9];
  const void* AIB  = d_in[10];
  const void* AOW  = d_in[11];
  const void* AOB  = d_in[12];
  const void* LNG  = d_in[13];
  const void* LNB  = d_in[14];
  const void* WOUT = d_in[15];
  const void* BOUT = d_in[16];
  const int* STEP  = (const int*)d_in[17];

  // ws layout (float offsets), total ~75.6 MB (unchanged)
  float* ws = (float*)d_ws;
  float* scal  = ws;                  // 64
  float* probs = ws + 64;
  float* ph    = ws + 64 + 2048;
  float* fmean = ws + 64 + 4096;
  float* xp    = ws + 64 + 12288;
  float* cells = ws + 16384;           // 2M f (dead after cellsB_kernel -> reused as Vp)
  float* CB    = ws + 16384 + 2097152; // 16.78M f region
  // phase 1:
  float* ar = CB;
  float* ai = CB + 4194304;
  float* cr = CB + 8388608;
  float* ci = CB + 12582912;
  // phase 2 (aliases phase 1):
  float* cellsB   = CB;                                   // [0 .. 4M)
  U16*   qkv16    = (U16*)(CB + 4194304);                 // [4M .. 10.49M) x U16; K/V stripes dead after pack -> O half1
  float* proj     = CB + 4194304;                         // aliases dead qkv
  float* O32a     = CB + 10485760;                        // [10.49 .. 14.68M) f32 partial O half0
  U16*   cellsB16 = (U16*)(CB + 12582912);                // rebuilt by ln each layer (dead during attn)
  U16*   Kp       = (U16*)(CB + 14680064);                // [14.68 .. 16.78M) = 4M U16; after attn reused as O16
  U16*   Vp       = (U16*)cells;                          // cells region dead in phase 2: 4M U16
  U16*   O16      = Kp;                                   // bf16 normalized O (Kp dead post-attn)
  float* zg       = (float*)d_out;                        // scratch: z[32768] + G[262144]
  U16*   Wd16     = (U16*)d_out;                          // per-phase bf16 weight scratch (AIW: before zg; AOW: after gram_fin)
  U16*   WOUT16   = (U16*)proj;                           // proj dead after last ln

  init_kernel<<<1, 256, 0, stream>>>(X, (const U16*)LNG, scal);

  for (int w = 0; w < 2; ++w) {
    if (w == 0) walk_coined_kernel<<<8192, 256, 0, stream>>>(AR, AI, cr, ci, CRc, CIc, scal, 0);
    else        walk_coined_kernel<<<8192, 256, 0, stream>>>(ar, ai, cr, ci, CRc, CIc, scal, 1);
    walk_new_stats_kernel<<<2048, 256, 0, stream>>>(cr, ci, ar, ai, scal, scal, 1 + w, probs, ph);
    inject_cells_kernel<<<4096, 256, 0, stream>>>(w == 0 ? CE : (const void*)cells, cells,
                                                  probs, ph, scal, 1 + w, w == 0 ? 1 : 0);
  }
  frustration_kernel<<<1024, 64, 0, stream>>>(cells, FS, scal);
  standing_kernel<<<8192, 256, 0, stream>>>(cells, STEP);
  morphism_kernel<<<1024, 64, 0, stream>>>(cells, STEP);
  faction_mean_kernel<<<32, 256, 0, stream>>>(cells, fmean);
  faction_apply_kernel<<<8192, 256, 0, stream>>>(cells, fmean, STEP);

  xproj_kernel<<<8, 256, 0, stream>>>(X, WIN, BIN, xp, scal);
  cellsB_kernel<<<16384, 256, 0, stream>>>(cells, xp, cellsB, cellsB16);
  // cells region now dead -> Vp

  for (int l = 0; l < 2; ++l) {
    // AIW bf16 into d_out scratch (dead until zero_zg)
    wcvt_kernel<<<3072, 256, 0, stream>>>(AIW, (long)l * 3072 * 1024, Wd16, 786432, scal);
    mfma_gemm_kernel<<<dim3(24, 32), 256, 0, stream>>>(cellsB16, AIW, (long)l * 3072 * 1024, Wd16,
                                                       AIB, (long)l * 3072, qkv16, 3072, 1, scal);
    pack_kv_kernel<<<dim3(32, 16, 2), 256, 0, stream>>>(qkv16, Kp, Vp);
    zero_zg_kernel<<<1152, 256, 0, stream>>>(zg);
    attn_mfma_kernel<<<256, 1024, 0, stream>>>(qkv16, Kp, Vp, O32a, zg);
    attn_norm_kernel<<<4096, 256, 0, stream>>>(O32a, qkv16, zg, O16);
    gram_fin_kernel<<<64, 256, 0, stream>>>(zg, scal, 8 + l);
    // AOW bf16 into d_out scratch (zg dead after gram_fin)
    wcvt_kernel<<<1024, 256, 0, stream>>>(AOW, (long)l * 1024 * 1024, Wd16, 262144, scal);
    mfma_gemm_kernel<<<dim3(8, 32), 256, 0, stream>>>(O16, AOW, (long)l * 1024 * 1024, Wd16,
                                                      AOB, (long)l * 1024, proj, 1024, 0, scal);
    ln_kernel<<<4096, 256, 0, stream>>>(cellsB, cellsB16, proj, LNG, LNB, (long)l * 1024, scal);
  }
  // WOUT bf16 into dead proj region (final gemm writes d_out)
  wcvt_kernel<<<512, 256, 0, stream>>>(WOUT, 0, WOUT16, 131072, scal);
  mfma_gemm_kernel<<<dim3(4, 32), 256, 0, stream>>>(cellsB16, WOUT, 0, WOUT16,
                                                    BOUT, 0, d_out, 512, 2, scal);
  tension_kernel<<<1, 1, 0, stream>>>(scal, d_out);
}